// Round 3
// baseline (383.547 us; speedup 1.0000x reference)
//
#include <hip/hip_runtime.h>
#include <hip/hip_bf16.h>
#include <math.h>

namespace {
constexpr int kDModel = 2048;
constexpr int kHeads  = 32;
constexpr int kState  = 64;
constexpr int kP      = 64;    // head dim = D_MODEL / N_HEADS
constexpr int kChunk  = 256;
constexpr int kNChunk = 16;    // SEQLEN / CHUNK
constexpr int kBatch  = 2;
constexpr int kSeq    = 4096;
constexpr int kM      = kBatch * kSeq;  // 8192 rows
}

typedef __bf16 bf16_t;
typedef __attribute__((ext_vector_type(8))) __bf16 bf16x8;
typedef __attribute__((ext_vector_type(4))) __bf16 bf16x4;
typedef __attribute__((ext_vector_type(4))) float f32x4;
typedef __attribute__((ext_vector_type(16))) float f32x16;

__device__ __forceinline__ void gload_lds16(const void* g, void* l) {
    __builtin_amdgcn_global_load_lds(
        (const __attribute__((address_space(1))) void*)g,
        (__attribute__((address_space(3))) void*)l,
        16, 0, 0);
}

// ---------------------------------------------------------------------------
// B/C/dt projection GEMM: 64x128 tile -> grid (2, 128) = 256 blocks.
// ---------------------------------------------------------------------------
__global__ __launch_bounds__(256)
void gemm_bcdt(const bf16_t* __restrict__ A, const bf16_t* __restrict__ W,
               const float* __restrict__ b0, const float* __restrict__ b1,
               const float* __restrict__ b2,
               bf16_t* __restrict__ o0h, bf16_t* __restrict__ o1h,
               float* __restrict__ o2f)
{
    constexpr int K = kDModel;
    __shared__ __bf16 AstS[64 * 32];
    __shared__ __bf16 WstS[128 * 32];
    const int tid  = threadIdx.x;
    const int lane = tid & 63;
    const int wave = tid >> 6;
    const int wm = (wave >> 1) * 32;
    const int wn = (wave & 1) * 64;
    const int l15 = lane & 15, quad = lane >> 4;
    const int m0 = blockIdx.y * 64;
    const int n0 = blockIdx.x * 128;
    const int u0 = tid, u1 = tid + 256;   // W staging 16B units

    f32x4 acc[2][4];
    #pragma unroll
    for (int i = 0; i < 2; ++i)
        #pragma unroll
        for (int j = 0; j < 4; ++j)
            acc[i][j] = (f32x4){0.f, 0.f, 0.f, 0.f};

    for (int k0 = 0; k0 < K; k0 += 32) {
        gload_lds16(A + (size_t)(m0 + (tid >> 2)) * K + k0 + (tid & 3) * 8, AstS + tid * 8);
        gload_lds16(W + (size_t)(n0 + (u0 >> 2)) * K + k0 + (u0 & 3) * 8, WstS + u0 * 8);
        gload_lds16(W + (size_t)(n0 + (u1 >> 2)) * K + k0 + (u1 & 3) * 8, WstS + u1 * 8);
        __syncthreads();
        bf16x8 af[2], bfr[4];
        #pragma unroll
        for (int mi = 0; mi < 2; ++mi)
            af[mi] = *reinterpret_cast<const bf16x8*>(&AstS[(wm + mi * 16 + l15) * 32 + quad * 8]);
        #pragma unroll
        for (int ni = 0; ni < 4; ++ni)
            bfr[ni] = *reinterpret_cast<const bf16x8*>(&WstS[(wn + ni * 16 + l15) * 32 + quad * 8]);
        #pragma unroll
        for (int mi = 0; mi < 2; ++mi)
            #pragma unroll
            for (int ni = 0; ni < 4; ++ni)
                acc[mi][ni] = __builtin_amdgcn_mfma_f32_16x16x32_bf16(
                    af[mi], bfr[ni], acc[mi][ni], 0, 0, 0);
        __syncthreads();
    }

    #pragma unroll
    for (int mi = 0; mi < 2; ++mi) {
        #pragma unroll
        for (int reg = 0; reg < 4; ++reg) {
            const int r = m0 + wm + mi * 16 + quad * 4 + reg;
            #pragma unroll
            for (int ni = 0; ni < 4; ++ni) {
                const float v = acc[mi][ni][reg];
                const int n = n0 + wn + ni * 16 + l15;
                if (n < 64) {
                    o0h[(size_t)r * 64 + n] = (bf16_t)(v + b0[n]);
                } else if (n < 128) {
                    o1h[(size_t)r * 64 + (n - 64)] = (bf16_t)(v + b1[n - 64]);
                } else if (n < 160) {
                    float z = v + b2[n - 128];
                    o2f[(size_t)r * 32 + (n - 128)] = (z > 20.f) ? z : log1pf(expf(z));
                }
            }
        }
    }
}

// ---------------------------------------------------------------------------
// Out-projection GEMM: 256x256 tile, BK=32, 8 waves (2Mx4N), triple-buffered
// LDS (96KB), raw s_barrier + counted vmcnt(4), slot-major LDS layout
// (conflict-free, verified). NOW 32x32x16 MFMA (4060 FLOP/cy vs 3378 for
// 16x16x32, same ds_read count) — sync skeleton identical to R1/R2.
//   Ap[ks][m][8], Bp[ks][n][8]  (ks = k/8)
// m-panel-per-XCD swizzle (verified: FETCH 135->49 MB).
// ---------------------------------------------------------------------------
__global__ __launch_bounds__(512, 2)
void gemm256_out(const bf16_t* __restrict__ Ap, const bf16_t* __restrict__ Bp,
                 const float* __restrict__ bias, float* __restrict__ C)
{
    constexpr int M = 8192, N = 2048, NT = 2048 / 32;  // 64 K-tiles
    __shared__ __bf16 Ab[3][4 * 256 * 8];   // [buf][slot*256 + row][8]
    __shared__ __bf16 Bb[3][4 * 256 * 8];
    const int tid  = threadIdx.x;
    const int lane = tid & 63;
    const int wave = tid >> 6;
    const int row32 = lane & 31, half = lane >> 5;
    const int bid = blockIdx.x;
    const int mt = (bid & 7) * 4 + ((bid >> 3) & 3);   // 0..31
    const int nt = bid >> 5;                           // 0..7
    const int m0 = mt * 256;
    const int n0 = nt * 256;
    const int wm = (wave >> 2) * 128;   // 0 or 128
    const int wn = (wave & 3) * 64;     // 0,64,128,192

    const int u0 = tid, u1 = tid + 512;   // staging 16B units
    auto stage = [&](int t2, int stb) {
        const int ks0 = t2 * 4;
        const bf16_t* As = Ap + ((size_t)ks0 * M + m0) * 8;
        const bf16_t* Bs = Bp + ((size_t)ks0 * N + n0) * 8;
        __bf16* Al = &Ab[stb][0];
        __bf16* Bl = &Bb[stb][0];
        gload_lds16(As + ((size_t)(u0 >> 8) * M + (u0 & 255)) * 8, Al + u0 * 8);
        gload_lds16(As + ((size_t)(u1 >> 8) * M + (u1 & 255)) * 8, Al + u1 * 8);
        gload_lds16(Bs + ((size_t)(u0 >> 8) * N + (u0 & 255)) * 8, Bl + u0 * 8);
        gload_lds16(Bs + ((size_t)(u1 >> 8) * N + (u1 & 255)) * 8, Bl + u1 * 8);
    };

    f32x16 acc[4][2];
    #pragma unroll
    for (int i = 0; i < 4; ++i)
        #pragma unroll
        for (int j = 0; j < 2; ++j)
            #pragma unroll
            for (int e = 0; e < 16; ++e)
                acc[i][j][e] = 0.f;

    stage(0, 0);
    stage(1, 1);
    asm volatile("s_waitcnt vmcnt(4)" ::: "memory");
    __builtin_amdgcn_s_barrier();

    int cur = 0;
    for (int t = 0; t < NT; ++t) {
        const __bf16* Ac = &Ab[cur][0];
        const __bf16* Bc = &Bb[cur][0];
        int stb = cur + 2; if (stb >= 3) stb -= 3;

        // ---- phase A: k-step 0 (slots {0,1}, lane-half selects slot)
        bf16x8 af[4], bfr[2];
        #pragma unroll
        for (int mf = 0; mf < 4; ++mf)
            af[mf] = *reinterpret_cast<const bf16x8*>(
                &Ac[(half * 256 + wm + mf * 32 + row32) * 8]);
        #pragma unroll
        for (int nf = 0; nf < 2; ++nf)
            bfr[nf] = *reinterpret_cast<const bf16x8*>(
                &Bc[(half * 256 + wn + nf * 32 + row32) * 8]);
        if (t < NT - 2) stage(t + 2, stb);
        __builtin_amdgcn_s_setprio(1);
        #pragma unroll
        for (int mf = 0; mf < 4; ++mf)
            #pragma unroll
            for (int nf = 0; nf < 2; ++nf)
                acc[mf][nf] = __builtin_amdgcn_mfma_f32_32x32x16_bf16(
                    af[mf], bfr[nf], acc[mf][nf], 0, 0, 0);
        __builtin_amdgcn_s_setprio(0);

        // ---- phase B: k-step 1 (slots {2,3})
        #pragma unroll
        for (int mf = 0; mf < 4; ++mf)
            af[mf] = *reinterpret_cast<const bf16x8*>(
                &Ac[((2 + half) * 256 + wm + mf * 32 + row32) * 8]);
        #pragma unroll
        for (int nf = 0; nf < 2; ++nf)
            bfr[nf] = *reinterpret_cast<const bf16x8*>(
                &Bc[((2 + half) * 256 + wn + nf * 32 + row32) * 8]);
        __builtin_amdgcn_s_setprio(1);
        #pragma unroll
        for (int mf = 0; mf < 4; ++mf)
            #pragma unroll
            for (int nf = 0; nf < 2; ++nf)
                acc[mf][nf] = __builtin_amdgcn_mfma_f32_32x32x16_bf16(
                    af[mf], bfr[nf], acc[mf][nf], 0, 0, 0);
        __builtin_amdgcn_s_setprio(0);

        // ---- tile boundary: tile t+1 landed; t+2's 4 loads may fly
        if (t < NT - 2) {
            asm volatile("s_waitcnt vmcnt(4)" ::: "memory");
        } else if (t < NT - 1) {
            asm volatile("s_waitcnt vmcnt(0)" ::: "memory");
        }
        if (t < NT - 1) __builtin_amdgcn_s_barrier();
        cur = cur + 1; if (cur == 3) cur = 0;
    }

    // epilogue: C/D layout 32x32: col=lane&31, row=(reg&3)+8*(reg>>2)+4*half
    float bia[2];
    #pragma unroll
    for (int nf = 0; nf < 2; ++nf) bia[nf] = bias[n0 + wn + nf * 32 + row32];
    #pragma unroll
    for (int mf = 0; mf < 4; ++mf) {
        #pragma unroll
        for (int nf = 0; nf < 2; ++nf) {
            #pragma unroll
            for (int reg = 0; reg < 16; ++reg) {
                const int r = m0 + wm + mf * 32 + (reg & 3) + 8 * (reg >> 2) + 4 * half;
                const int c = n0 + wn + nf * 32 + row32;
                C[(size_t)r * N + c] = acc[mf][nf][reg] + bia[nf];
            }
        }
    }
}

// float -> bf16 convert, 4 elems/thread
__global__ __launch_bounds__(256)
void cvt_bf16_kernel(const float* __restrict__ src, bf16_t* __restrict__ dst, int n)
{
    const int i = (blockIdx.x * 256 + threadIdx.x) * 4;
    if (i + 3 < n) {
        const float4 v = *reinterpret_cast<const float4*>(src + i);
        dst[i + 0] = (bf16_t)v.x;
        dst[i + 1] = (bf16_t)v.y;
        dst[i + 2] = (bf16_t)v.z;
        dst[i + 3] = (bf16_t)v.w;
    }
}

// out_w fp32 [2048][2048] -> slot-major bf16 Wp[ks][n][8]
__global__ __launch_bounds__(256)
void pack_wob_kernel(const float* __restrict__ W, bf16_t* __restrict__ Wp)
{
    const int idx = blockIdx.x * 256 + threadIdx.x;
    const int n = idx >> 8, ks = idx & 255;
    const float4 v0 = *reinterpret_cast<const float4*>(W + (size_t)n * 2048 + ks * 8);
    const float4 v1 = *reinterpret_cast<const float4*>(W + (size_t)n * 2048 + ks * 8 + 4);
    bf16x8 o;
    o[0] = (__bf16)v0.x; o[1] = (__bf16)v0.y; o[2] = (__bf16)v0.z; o[3] = (__bf16)v0.w;
    o[4] = (__bf16)v1.x; o[5] = (__bf16)v1.y; o[6] = (__bf16)v1.z; o[7] = (__bf16)v1.w;
    *reinterpret_cast<bf16x8*>(Wp + ((size_t)ks * 2048 + n) * 8) = o;
}

// Concat [B_w;C_w;dt_w] into bf16 [256,2048], rows 160..255 zero
__global__ __launch_bounds__(256)
void pack_w_kernel(const float* __restrict__ B_w, const float* __restrict__ C_w,
                   const float* __restrict__ dt_w, bf16_t* __restrict__ wcat)
{
    const int idx = blockIdx.x * 256 + threadIdx.x;
    const int r = idx >> 11, k = idx & 2047;
    float v = 0.f;
    if (r < 64)       v = B_w[r * 2048 + k];
    else if (r < 128) v = C_w[(r - 64) * 2048 + k];
    else if (r < 160) v = dt_w[(r - 128) * 2048 + k];
    wcat[idx] = (bf16_t)v;
}

// Per (b,h,chunk): Acs[l] = inclusive cumsum_l( dt[l] * A[h] ), A = -exp(A_log)
__global__ __launch_bounds__(kChunk)
void dtcumsum_kernel(const float* __restrict__ dtm, const float* __restrict__ A_log,
                     float* __restrict__ Acs)
{
    const int blk = blockIdx.x;
    const int ci = blk & (kNChunk - 1);
    const int hi = (blk >> 4) & (kHeads - 1);
    const int bi = blk >> 9;
    const int t = threadIdx.x;
    const float Ah = -expf(A_log[hi]);
    __shared__ float s[kChunk];
    s[t] = dtm[((size_t)bi * kSeq + ci * kChunk + t) * kHeads + hi] * Ah;
    __syncthreads();
    for (int off = 1; off < kChunk; off <<= 1) {
        const float add = (t >= off) ? s[t - off] : 0.f;
        __syncthreads();
        s[t] += add;
        __syncthreads();
    }
    Acs[((size_t)(bi * kHeads + hi) * kNChunk + ci) * kChunk + t] = s[t];
}

// Transpose one chunk of B: bTg[b,c][n][l] = Bb16[(b,c,l)][n]
__global__ __launch_bounds__(256)
void bT_kernel(const bf16_t* __restrict__ Bb16, bf16_t* __restrict__ bTg)
{
    const int ci = blockIdx.x & (kNChunk - 1);
    const int bi = blockIdx.x >> 4;
    const size_t rowbase = (size_t)bi * kSeq + ci * kChunk;
    __shared__ __bf16 T[64 * 264];
    const int tid = threadIdx.x;
    bf16x8 v[8];
    #pragma unroll
    for (int e = 0; e < 8; ++e)
        v[e] = *reinterpret_cast<const bf16x8*>(Bb16 + (rowbase + tid) * 64 + e * 8);
    #pragma unroll
    for (int e = 0; e < 8; ++e)
        #pragma unroll
        for (int j = 0; j < 8; ++j)
            T[(e * 8 + j) * 264 + tid] = v[e][j];
    __syncthreads();
    const int n = tid >> 2, seg = (tid & 3) * 64;
    bf16_t* dst = bTg + ((size_t)(bi * kNChunk + ci)) * (64 * 256) + n * 256 + seg;
    #pragma unroll
    for (int j = 0; j < 8; ++j) {
        *reinterpret_cast<bf16x8*>(dst + j * 8) =
            *reinterpret_cast<const bf16x8*>(&T[n * 264 + seg + j * 8]);
    }
}

// xdtT[(b,c,h)][p][l] = bf16( xb[t, h*64+p] * dt[t,h] ),  t = rowbase+l
__global__ __launch_bounds__(256)
void xdtT_kernel(const bf16_t* __restrict__ xb, const float* __restrict__ dtm,
                 bf16_t* __restrict__ xdtT)
{
    const int blk = blockIdx.x;
    const int hi = blk & (kHeads - 1);
    const int ci = (blk >> 5) & (kNChunk - 1);
    const int bi = blk >> 9;
    const size_t rowbase = (size_t)bi * kSeq + ci * kChunk;
    __shared__ __bf16 T[64 * 264];
    const int tid = threadIdx.x;
    const float d = dtm[(rowbase + tid) * kHeads + hi];
    bf16x8 v[8];
    #pragma unroll
    for (int e = 0; e < 8; ++e)
        v[e] = *reinterpret_cast<const bf16x8*>(xb + (rowbase + tid) * kDModel + hi * kP + e * 8);
    #pragma unroll
    for (int e = 0; e < 8; ++e)
        #pragma unroll
        for (int j = 0; j < 8; ++j)
            T[(e * 8 + j) * 264 + tid] = (__bf16)((float)v[e][j] * d);
    __syncthreads();
    const int p = tid >> 2, seg = (tid & 3) * 64;
    bf16_t* dst = xdtT + (size_t)blk * (64 * 256) + p * 256 + seg;
    #pragma unroll
    for (int j = 0; j < 8; ++j) {
        *reinterpret_cast<bf16x8*>(dst + j * 8) =
            *reinterpret_cast<const bf16x8*>(&T[p * 264 + seg + j * 8]);
    }
}

// ---------------------------------------------------------------------------
// MFMA chunk states: states[(b,c,h)][p][n] = sum_l xdtT[p][l]*dec[l]*B[l][n]
// ---------------------------------------------------------------------------
__global__ __launch_bounds__(256)
void states_mfma(const bf16_t* __restrict__ xdtT, const bf16_t* __restrict__ bTg,
                 const float* __restrict__ Acs, float* __restrict__ states)
{
    const int blk = blockIdx.x;
    const int hi = blk & (kHeads - 1);
    const int ci = (blk >> 5) & (kNChunk - 1);
    const int bi = blk >> 9;
    __shared__ __bf16 Xa[64 * 264];
    __shared__ __bf16 Bt[64 * 264];
    __shared__ float dec[kChunk];
    const int tid = threadIdx.x;
    const int lane = tid & 63;
    const int wave = tid >> 6;
    const int l15 = lane & 15, quad = lane >> 4;

    const float* acs = Acs + ((size_t)(bi * kHeads + hi) * kNChunk + ci) * kChunk;
    dec[tid] = expf(acs[kChunk - 1] - acs[tid]);   // <= 1
    __syncthreads();

    const bf16_t* bsrc = bTg + ((size_t)(bi * kNChunk + ci)) * (64 * 256);
    const bf16_t* xsrc = xdtT + (size_t)blk * (64 * 256);
    #pragma unroll
    for (int e = 0; e < 8; ++e) {
        const int u = e * 256 + tid;
        const int r = u >> 5, seg = (u & 31) * 8;
        *reinterpret_cast<bf16x8*>(&Bt[r * 264 + seg]) =
            *reinterpret_cast<const bf16x8*>(bsrc + r * 256 + seg);
        bf16x8 xv = *reinterpret_cast<const bf16x8*>(xsrc + r * 256 + seg);
        bf16x8 xo;
        #pragma unroll
        for (int j = 0; j < 8; ++j)
            xo[j] = (__bf16)((float)xv[j] * dec[seg + j]);
        *reinterpret_cast<bf16x8*>(&Xa[r * 264 + seg]) = xo;
    }
    __syncthreads();

    f32x4 acc[4];
    #pragma unroll
    for (int ni = 0; ni < 4; ++ni) acc[ni] = (f32x4){0.f, 0.f, 0.f, 0.f};
    #pragma unroll
    for (int kk = 0; kk < 8; ++kk) {
        const bf16x8 af = *reinterpret_cast<const bf16x8*>(
            &Xa[(wave * 16 + l15) * 264 + kk * 32 + quad * 8]);
        #pragma unroll
        for (int ni = 0; ni < 4; ++ni) {
            const bf16x8 bf = *reinterpret_cast<const bf16x8*>(
                &Bt[(ni * 16 + l15) * 264 + kk * 32 + quad * 8]);
            acc[ni] = __builtin_amdgcn_mfma_f32_16x16x32_bf16(af, bf, acc[ni], 0, 0, 0);
        }
    }
    float* sp = states + (size_t)blk * (kP * kState);
    #pragma unroll
    for (int reg = 0; reg < 4; ++reg) {
        const int p = wave * 16 + quad * 4 + reg;
        #pragma unroll
        for (int ni = 0; ni < 4; ++ni)
            sp[(size_t)p * kState + ni * 16 + l15] = acc[ni][reg];
    }
}

// prevs[b,0,h]=0 ; prevs[b,c,h] = exp(a[c-1])*prevs[b,c-1,h] + states[b,c-1,h]
// fp32 scan in registers, emits BF16 (rounding previously done in ychunk).
__global__ __launch_bounds__(256)
void chunkscan_kernel(const float* __restrict__ states, const float* __restrict__ Acs,
                      bf16_t* __restrict__ prevsb)
{
    const int q  = blockIdx.x & 15;
    const int hi = (blockIdx.x >> 4) & (kHeads - 1);
    const int bi = blockIdx.x >> 9;
    const int e  = q * 256 + threadIdx.x;          // element in [0, 4096)
    __shared__ float ea[kNChunk];
    if (threadIdx.x < kNChunk)
        ea[threadIdx.x] = expf(Acs[((size_t)(bi * kHeads + hi) * kNChunk + threadIdx.x)
                                   * kChunk + kChunk - 1]);
    __syncthreads();
    float P = 0.f;
    prevsb[((size_t)(bi * kNChunk + 0) * kHeads + hi) * (kP * kState) + e] = (bf16_t)0.f;
    for (int c = 1; c < kNChunk; ++c) {
        P = fmaf(ea[c - 1], P,
                 states[((size_t)(bi * kNChunk + (c - 1)) * kHeads + hi) * (kP * kState) + e]);
        prevsb[((size_t)(bi * kNChunk + c) * kHeads + hi) * (kP * kState) + e] = (bf16_t)P;
    }
}

// ---------------------------------------------------------------------------
// MFMA intra-chunk Y, MERGED over lt: one block per (b,c,h), grid 1024.
// st-outer / lt-inner: each B/Xt s-tile staged ONCE (was lt+1 times), P
// staged once as bf16 (was 4x as fp32). Epilogue x recovered as xdt/dt from
// the resident Xt slice at st==lt (removes the 67 MB fp32 x read).
// yacc[4][4] with lt fully unrolled (no runtime-indexed regs, rule #20).
// Output written SLOT-MAJOR: Yp[(hi*8+p/8)*kM + t][p%8].
// ---------------------------------------------------------------------------
__global__ __launch_bounds__(256)
void ychunk_mfma(const bf16_t* __restrict__ Bb16, const bf16_t* __restrict__ Cb16,
                 const bf16_t* __restrict__ xdtT, const float* __restrict__ Acs,
                 const bf16_t* __restrict__ prevsb, const float* __restrict__ dtm,
                 const float* __restrict__ Dvec, bf16_t* __restrict__ Yp)
{
    const int blk = blockIdx.x;                  // (bi*16+ci)*32+hi
    const int hi = blk & (kHeads - 1);
    const int ci = (blk >> 5) & (kNChunk - 1);
    const int bi = blk >> 9;
    __shared__ float acs_s[kChunk];
    __shared__ float dts[kChunk];
    __shared__ __bf16 Cs[256 * 72];  // full C chunk tile [l][n]
    __shared__ __bf16 Ps[64 * 72];   // prev-state [p][n]
    __shared__ __bf16 Bs[64 * 72];   // B s-tile [s][n]
    __shared__ __bf16 Xt[64 * 72];   // XdtT [p][s]
    __shared__ __bf16 Sp[64 * 72];   // S' [l][s]
    const int tid = threadIdx.x;
    const int lane = tid & 63;
    const int wave = tid >> 6;
    const int l15 = lane & 15, quad = lane >> 4;
    const int mrow = wave * 16 + quad * 4;       // row-in-64-tile base
    const size_t rowbase = (size_t)bi * kSeq + ci * kChunk;
    const bf16_t* xdsrc = xdtT + (size_t)blk * (64 * 256);

    acs_s[tid] = Acs[((size_t)(bi * kHeads + hi) * kNChunk + ci) * kChunk + tid];
    dts[tid]   = dtm[(rowbase + tid) * kHeads + hi];
    // stage full C chunk (8 units) and P bf16 (2 units)
    #pragma unroll
    for (int e = 0; e < 8; ++e) {
        const int u = e * 256 + tid;
        const int r = u >> 3, seg = (u & 7) * 8;
        *reinterpret_cast<bf16x8*>(&Cs[r * 72 + seg]) =
            *reinterpret_cast<const bf16x8*>(Cb16 + (rowbase + r) * 64 + seg);
    }
    const bf16_t* pp = prevsb + ((size_t)(bi * kNChunk + ci) * kHeads + hi) * (kP * kState);
    #pragma unroll
    for (int e = 0; e < 2; ++e) {
        const int u = e * 256 + tid;
        const int r = u >> 3, seg = (u & 7) * 8;
        *reinterpret_cast<bf16x8*>(&Ps[r * 72 + seg]) =
            *reinterpret_cast<const bf16x8*>(pp + r * 64 + seg);
    }
    __syncthreads();

    // Y_off[lt] = (C_lt @ P^T) * exp(acs[l])
    f32x4 yacc[4][4];
    #pragma unroll
    for (int lt = 0; lt < 4; ++lt) {
        #pragma unroll
        for (int ni = 0; ni < 4; ++ni) yacc[lt][ni] = (f32x4){0.f, 0.f, 0.f, 0.f};
        const bf16x8 af0 = *reinterpret_cast<const bf16x8*>(
            &Cs[(lt * 64 + wave * 16 + l15) * 72 + quad * 8]);
        const bf16x8 af1 = *reinterpret_cast<const bf16x8*>(
            &Cs[(lt * 64 + wave * 16 + l15) * 72 + 32 + quad * 8]);
        #pragma unroll
        for (int ni = 0; ni < 4; ++ni) {
            const bf16x8 b0 = *reinterpret_cast<const bf16x8*>(&Ps[(ni * 16 + l15) * 72 + quad * 8]);
            const bf16x8 b1 = *reinterpret_cast<const bf16x8*>(&Ps[(ni * 16 + l15) * 72 + 32 + quad * 8]);
            yacc[lt][ni] = __builtin_amdgcn_mfma_f32_16x16x32_bf16(af0, b0, yacc[lt][ni], 0, 0, 0);
            yacc[lt][ni] = __builtin_amdgcn_mfma_f32_16x16x32_bf16(af1, b1, yacc[lt][ni], 0, 0, 0);
        }
        float es[4];
        #pragma unroll
        for (int reg = 0; reg < 4; ++reg) es[reg] = expf(acs_s[lt * 64 + mrow + reg]);
        #pragma unroll
        for (int ni = 0; ni < 4; ++ni)
            #pragma unroll
            for (int reg = 0; reg < 4; ++reg) yacc[lt][ni][reg] *= es[reg];
    }

    const float Dh = Dvec[hi];
    for (int st = 0; st < 4; ++st) {
        __syncthreads();   // prior readers of Bs/Xt done
        #pragma unroll
        for (int e = 0; e < 2; ++e) {
            const int u = e * 256 + tid;
            const int r = u >> 3, seg = (u & 7) * 8;
            *reinterpret_cast<bf16x8*>(&Bs[r * 72 + seg]) =
                *reinterpret_cast<const bf16x8*>(Bb16 + (rowbase + st * 64 + r) * 64 + seg);
            *reinterpret_cast<bf16x8*>(&Xt[r * 72 + seg]) =
                *reinterpret_cast<const bf16x8*>(xdsrc + r * 256 + st * 64 + seg);
        }
        __syncthreads();
        #pragma unroll
        for (int lt = 0; lt < 4; ++lt) {
            if (lt < st) continue;               // block-uniform: barriers safe
            const bf16x8 af0 = *reinterpret_cast<const bf16x8*>(
                &Cs[(lt * 64 + wave * 16 + l15) * 72 + quad * 8]);
            const bf16x8 af1 = *reinterpret_cast<const bf16x8*>(
                &Cs[(lt * 64 + wave * 16 + l15) * 72 + 32 + quad * 8]);
            // S = C_lt @ B_st^T
            f32x4 sacc[4];
            #pragma unroll
            for (int ni = 0; ni < 4; ++ni) sacc[ni] = (f32x4){0.f, 0.f, 0.f, 0.f};
            #pragma unroll
            for (int ni = 0; ni < 4; ++ni) {
                const bf16x8 b0 = *reinterpret_cast<const bf16x8*>(&Bs[(ni * 16 + l15) * 72 + quad * 8]);
                const bf16x8 b1 = *reinterpret_cast<const bf16x8*>(&Bs[(ni * 16 + l15) * 72 + 32 + quad * 8]);
                sacc[ni] = __builtin_amdgcn_mfma_f32_16x16x32_bf16(af0, b0, sacc[ni], 0, 0, 0);
                sacc[ni] = __builtin_amdgcn_mfma_f32_16x16x32_bf16(af1, b1, sacc[ni], 0, 0, 0);
            }
            // decay + causal mask -> S' bf16
            #pragma unroll
            for (int reg = 0; reg < 4; ++reg) {
                const int l = lt * 64 + mrow + reg;
                const float al = acs_s[l];
                #pragma unroll
                for (int ni = 0; ni < 4; ++ni) {
                    const int scol = ni * 16 + l15;
                    const int sg = st * 64 + scol;
                    float v = sacc[ni][reg] * expf(al - acs_s[sg]);
                    if (st == lt && sg > l) v = 0.f;
                    Sp[(mrow + reg) * 72 + scol] = (__bf16)v;
                }
            }
            __syncthreads();   // S' visible before reads
            const bf16x8 as0 = *reinterpret_cast<const bf16x8*>(&Sp[(wave * 16 + l15) * 72 + quad * 8]);
            const bf16x8 as1 = *reinterpret_cast<const bf16x8*>(&Sp[(wave * 16 + l15) * 72 + 32 + quad * 8]);
            #pragma unroll
            for (int ni = 0; ni < 4; ++ni) {
                const bf16x8 x0 = *reinterpret_cast<const bf16x8*>(&Xt[(ni * 16 + l15) * 72 + quad * 8]);
                const bf16x8 x1 = *reinterpret_cast<const bf16x8*>(&Xt[(ni * 16 + l15) * 72 + 32 + quad * 8]);
                yacc[lt][ni] = __builtin_amdgcn_mfma_f32_16x16x32_bf16(as0, x0, yacc[lt][ni], 0, 0, 0);
                yacc[lt][ni] = __builtin_amdgcn_mfma_f32_16x16x32_bf16(as1, x1, yacc[lt][ni], 0, 0, 0);
            }
            if (lt == st) {
                // yacc[lt] complete (st = 0..lt delivered). Epilogue:
                // x = xdt/dt from the resident Xt slice (st == lt).
                #pragma unroll
                for (int reg = 0; reg < 4; ++reg) {
                    const int lrow = mrow + reg;
                    const size_t tg = rowbase + lt * 64 + lrow;
                    const float dinv = 1.f / dts[lt * 64 + lrow];
                    #pragma unroll
                    for (int ni = 0; ni < 4; ++ni) {
                        const int p = ni * 16 + l15;
                        const float xv = (float)Xt[p * 72 + lrow] * dinv;
                        const float v = yacc[lt][ni][reg] + Dh * xv;
                        Yp[((size_t)(hi * 8 + (p >> 3)) * (size_t)kM + tg) * 8 + (p & 7)] = (bf16_t)v;
                    }
                }
            }
            __syncthreads();   // Sp reads (and epilogue Xt reads) done
        }
    }
}

extern "C" void kernel_launch(void* const* d_in, const int* in_sizes, int n_in,
                              void* d_out, int out_size, void* d_ws, size_t ws_size,
                              hipStream_t stream)
{
    (void)in_sizes; (void)n_in; (void)out_size; (void)ws_size;
    const float* x     = (const float*)d_in[0];
    const float* A_log = (const float*)d_in[1];
    const float* Dvec  = (const float*)d_in[2];
    const float* B_w   = (const float*)d_in[3];
    const float* B_b   = (const float*)d_in[4];
    const float* C_w   = (const float*)d_in[5];
    const float* C_b   = (const float*)d_in[6];
    const float* dt_w  = (const float*)d_in[7];
    const float* dt_b  = (const float*)d_in[8];
    const float* out_w = (const float*)d_in[9];
    const float* out_b = (const float*)d_in[10];
    float* out = (float*)d_out;

    // workspace layout
    float* ws = (float*)d_ws;
    float* dtm    = ws;                                                  // 2*4096*32
    float* Acs    = dtm + (size_t)kM * kHeads;                           // 2*32*16*256
    float* states = Acs + (size_t)kBatch * kHeads * kNChunk * kChunk;    // fp32 states
    bf16_t* prevsb = (bf16_t*)(states + (size_t)kBatch * kNChunk * kHeads * kP * kState);
    bf16_t* xb    = prevsb + (size_t)kBatch * kNChunk * kHeads * kP * kState;
    bf16_t* Y     = xb;                               // ALIAS: xb dead after xdtT_kernel
    bf16_t* Bb16  = xb + (size_t)kM * kDModel;        // [t][64]
    bf16_t* Cb16  = Bb16 + (size_t)kM * kState;       // [t][64]
    bf16_t* xdtT  = Cb16 + (size_t)kM * kState;       // [(b,c,h)][64][256]
    bf16_t* bTg   = xdtT + (size_t)kM * kDModel;      // [(b,c)][64][256]
    bf16_t* wcat  = bTg + (size_t)kBatch * kNChunk * kState * kChunk;
    bf16_t* wob   = wcat + (size_t)256 * kDModel;     // bf16 out_w, slot-major [256][2048][8]

    const dim3 blk(256);
    cvt_bf16_kernel<<<dim3(kM * kDModel / 1024), blk, 0, stream>>>(x, xb, kM * kDModel);
    pack_wob_kernel<<<dim3(kDModel * 256 / 256), blk, 0, stream>>>(out_w, wob);
    pack_w_kernel<<<dim3(256 * kDModel / 256), blk, 0, stream>>>(B_w, C_w, dt_w, wcat);
    gemm_bcdt<<<dim3(2, kM / 64), blk, 0, stream>>>(xb, wcat, B_b, C_b, dt_b,
                                                    Bb16, Cb16, dtm);
    dtcumsum_kernel<<<dim3(kBatch * kHeads * kNChunk), dim3(kChunk), 0, stream>>>(dtm, A_log, Acs);
    bT_kernel<<<dim3(kBatch * kNChunk), blk, 0, stream>>>(Bb16, bTg);
    xdtT_kernel<<<dim3(kBatch * kNChunk * kHeads), blk, 0, stream>>>(xb, dtm, xdtT);
    states_mfma<<<dim3(kBatch * kNChunk * kHeads), blk, 0, stream>>>(xdtT, bTg, Acs, states);
    chunkscan_kernel<<<dim3(kBatch * kHeads * 16), blk, 0, stream>>>(states, Acs, prevsb);
    // merged intra-chunk Y: one block per (b,c,h)
    ychunk_mfma<<<dim3(kBatch * kNChunk * kHeads), blk, 0, stream>>>(
        Bb16, Cb16, xdtT, Acs, prevsb, dtm, Dvec, Y);
    gemm256_out<<<dim3(256), dim3(512), 0, stream>>>(Y, wob, out_b, out);
}

// Round 4
// 364.736 us; speedup vs baseline: 1.0516x; 1.0516x over previous
//
#include <hip/hip_runtime.h>
#include <hip/hip_bf16.h>
#include <math.h>

namespace {
constexpr int kDModel = 2048;
constexpr int kHeads  = 32;
constexpr int kState  = 64;
constexpr int kP      = 64;    // head dim = D_MODEL / N_HEADS
constexpr int kChunk  = 256;
constexpr int kNChunk = 16;    // SEQLEN / CHUNK
constexpr int kBatch  = 2;
constexpr int kSeq    = 4096;
constexpr int kM      = kBatch * kSeq;  // 8192 rows
}

typedef __bf16 bf16_t;
typedef __attribute__((ext_vector_type(8))) __bf16 bf16x8;
typedef __attribute__((ext_vector_type(4))) __bf16 bf16x4;
typedef __attribute__((ext_vector_type(4))) float f32x4;
typedef __attribute__((ext_vector_type(16))) float f32x16;

__device__ __forceinline__ void gload_lds16(const void* g, void* l) {
    __builtin_amdgcn_global_load_lds(
        (const __attribute__((address_space(1))) void*)g,
        (__attribute__((address_space(3))) void*)l,
        16, 0, 0);
}

// ---------------------------------------------------------------------------
// B/C/dt projection GEMM: 64x128 tile -> grid (2, 128) = 256 blocks.
// ---------------------------------------------------------------------------
__global__ __launch_bounds__(256)
void gemm_bcdt(const bf16_t* __restrict__ A, const bf16_t* __restrict__ W,
               const float* __restrict__ b0, const float* __restrict__ b1,
               const float* __restrict__ b2,
               bf16_t* __restrict__ o0h, bf16_t* __restrict__ o1h,
               float* __restrict__ o2f)
{
    constexpr int K = kDModel;
    __shared__ __bf16 AstS[64 * 32];
    __shared__ __bf16 WstS[128 * 32];
    const int tid  = threadIdx.x;
    const int lane = tid & 63;
    const int wave = tid >> 6;
    const int wm = (wave >> 1) * 32;
    const int wn = (wave & 1) * 64;
    const int l15 = lane & 15, quad = lane >> 4;
    const int m0 = blockIdx.y * 64;
    const int n0 = blockIdx.x * 128;
    const int u0 = tid, u1 = tid + 256;   // W staging 16B units

    f32x4 acc[2][4];
    #pragma unroll
    for (int i = 0; i < 2; ++i)
        #pragma unroll
        for (int j = 0; j < 4; ++j)
            acc[i][j] = (f32x4){0.f, 0.f, 0.f, 0.f};

    for (int k0 = 0; k0 < K; k0 += 32) {
        gload_lds16(A + (size_t)(m0 + (tid >> 2)) * K + k0 + (tid & 3) * 8, AstS + tid * 8);
        gload_lds16(W + (size_t)(n0 + (u0 >> 2)) * K + k0 + (u0 & 3) * 8, WstS + u0 * 8);
        gload_lds16(W + (size_t)(n0 + (u1 >> 2)) * K + k0 + (u1 & 3) * 8, WstS + u1 * 8);
        __syncthreads();
        bf16x8 af[2], bfr[4];
        #pragma unroll
        for (int mi = 0; mi < 2; ++mi)
            af[mi] = *reinterpret_cast<const bf16x8*>(&AstS[(wm + mi * 16 + l15) * 32 + quad * 8]);
        #pragma unroll
        for (int ni = 0; ni < 4; ++ni)
            bfr[ni] = *reinterpret_cast<const bf16x8*>(&WstS[(wn + ni * 16 + l15) * 32 + quad * 8]);
        #pragma unroll
        for (int mi = 0; mi < 2; ++mi)
            #pragma unroll
            for (int ni = 0; ni < 4; ++ni)
                acc[mi][ni] = __builtin_amdgcn_mfma_f32_16x16x32_bf16(
                    af[mi], bfr[ni], acc[mi][ni], 0, 0, 0);
        __syncthreads();
    }

    #pragma unroll
    for (int mi = 0; mi < 2; ++mi) {
        #pragma unroll
        for (int reg = 0; reg < 4; ++reg) {
            const int r = m0 + wm + mi * 16 + quad * 4 + reg;
            #pragma unroll
            for (int ni = 0; ni < 4; ++ni) {
                const float v = acc[mi][ni][reg];
                const int n = n0 + wn + ni * 16 + l15;
                if (n < 64) {
                    o0h[(size_t)r * 64 + n] = (bf16_t)(v + b0[n]);
                } else if (n < 128) {
                    o1h[(size_t)r * 64 + (n - 64)] = (bf16_t)(v + b1[n - 64]);
                } else if (n < 160) {
                    float z = v + b2[n - 128];
                    o2f[(size_t)r * 32 + (n - 128)] = (z > 20.f) ? z : log1pf(expf(z));
                }
            }
        }
    }
}

// ---------------------------------------------------------------------------
// Out-projection GEMM: 256x256 tile, BK=32, 8 waves (2Mx4N), triple-buffered
// LDS (96KB), raw s_barrier + counted vmcnt(4), slot-major LDS layout,
// 32x32x16 MFMA. m-panel-per-XCD swizzle (FETCH 135->49 MB verified).
// ---------------------------------------------------------------------------
__global__ __launch_bounds__(512, 2)
void gemm256_out(const bf16_t* __restrict__ Ap, const bf16_t* __restrict__ Bp,
                 const float* __restrict__ bias, float* __restrict__ C)
{
    constexpr int M = 8192, N = 2048, NT = 2048 / 32;  // 64 K-tiles
    __shared__ __bf16 Ab[3][4 * 256 * 8];   // [buf][slot*256 + row][8]
    __shared__ __bf16 Bb[3][4 * 256 * 8];
    const int tid  = threadIdx.x;
    const int lane = tid & 63;
    const int wave = tid >> 6;
    const int row32 = lane & 31, half = lane >> 5;
    const int bid = blockIdx.x;
    const int mt = (bid & 7) * 4 + ((bid >> 3) & 3);   // 0..31
    const int nt = bid >> 5;                           // 0..7
    const int m0 = mt * 256;
    const int n0 = nt * 256;
    const int wm = (wave >> 2) * 128;   // 0 or 128
    const int wn = (wave & 3) * 64;     // 0,64,128,192

    const int u0 = tid, u1 = tid + 512;   // staging 16B units
    auto stage = [&](int t2, int stb) {
        const int ks0 = t2 * 4;
        const bf16_t* As = Ap + ((size_t)ks0 * M + m0) * 8;
        const bf16_t* Bs = Bp + ((size_t)ks0 * N + n0) * 8;
        __bf16* Al = &Ab[stb][0];
        __bf16* Bl = &Bb[stb][0];
        gload_lds16(As + ((size_t)(u0 >> 8) * M + (u0 & 255)) * 8, Al + u0 * 8);
        gload_lds16(As + ((size_t)(u1 >> 8) * M + (u1 & 255)) * 8, Al + u1 * 8);
        gload_lds16(Bs + ((size_t)(u0 >> 8) * N + (u0 & 255)) * 8, Bl + u0 * 8);
        gload_lds16(Bs + ((size_t)(u1 >> 8) * N + (u1 & 255)) * 8, Bl + u1 * 8);
    };

    f32x16 acc[4][2];
    #pragma unroll
    for (int i = 0; i < 4; ++i)
        #pragma unroll
        for (int j = 0; j < 2; ++j)
            #pragma unroll
            for (int e = 0; e < 16; ++e)
                acc[i][j][e] = 0.f;

    stage(0, 0);
    stage(1, 1);
    asm volatile("s_waitcnt vmcnt(4)" ::: "memory");
    __builtin_amdgcn_s_barrier();

    int cur = 0;
    for (int t = 0; t < NT; ++t) {
        const __bf16* Ac = &Ab[cur][0];
        const __bf16* Bc = &Bb[cur][0];
        int stb = cur + 2; if (stb >= 3) stb -= 3;

        // ---- phase A: k-step 0 (slots {0,1}, lane-half selects slot)
        bf16x8 af[4], bfr[2];
        #pragma unroll
        for (int mf = 0; mf < 4; ++mf)
            af[mf] = *reinterpret_cast<const bf16x8*>(
                &Ac[(half * 256 + wm + mf * 32 + row32) * 8]);
        #pragma unroll
        for (int nf = 0; nf < 2; ++nf)
            bfr[nf] = *reinterpret_cast<const bf16x8*>(
                &Bc[(half * 256 + wn + nf * 32 + row32) * 8]);
        if (t < NT - 2) stage(t + 2, stb);
        __builtin_amdgcn_s_setprio(1);
        #pragma unroll
        for (int mf = 0; mf < 4; ++mf)
            #pragma unroll
            for (int nf = 0; nf < 2; ++nf)
                acc[mf][nf] = __builtin_amdgcn_mfma_f32_32x32x16_bf16(
                    af[mf], bfr[nf], acc[mf][nf], 0, 0, 0);
        __builtin_amdgcn_s_setprio(0);

        // ---- phase B: k-step 1 (slots {2,3})
        #pragma unroll
        for (int mf = 0; mf < 4; ++mf)
            af[mf] = *reinterpret_cast<const bf16x8*>(
                &Ac[((2 + half) * 256 + wm + mf * 32 + row32) * 8]);
        #pragma unroll
        for (int nf = 0; nf < 2; ++nf)
            bfr[nf] = *reinterpret_cast<const bf16x8*>(
                &Bc[((2 + half) * 256 + wn + nf * 32 + row32) * 8]);
        __builtin_amdgcn_s_setprio(1);
        #pragma unroll
        for (int mf = 0; mf < 4; ++mf)
            #pragma unroll
            for (int nf = 0; nf < 2; ++nf)
                acc[mf][nf] = __builtin_amdgcn_mfma_f32_32x32x16_bf16(
                    af[mf], bfr[nf], acc[mf][nf], 0, 0, 0);
        __builtin_amdgcn_s_setprio(0);

        // ---- tile boundary: tile t+1 landed; t+2's 4 loads may fly
        if (t < NT - 2) {
            asm volatile("s_waitcnt vmcnt(4)" ::: "memory");
        } else if (t < NT - 1) {
            asm volatile("s_waitcnt vmcnt(0)" ::: "memory");
        }
        if (t < NT - 1) __builtin_amdgcn_s_barrier();
        cur = cur + 1; if (cur == 3) cur = 0;
    }

    // epilogue: C/D layout 32x32: col=lane&31, row=(reg&3)+8*(reg>>2)+4*half
    float bia[2];
    #pragma unroll
    for (int nf = 0; nf < 2; ++nf) bia[nf] = bias[n0 + wn + nf * 32 + row32];
    #pragma unroll
    for (int mf = 0; mf < 4; ++mf) {
        #pragma unroll
        for (int nf = 0; nf < 2; ++nf) {
            #pragma unroll
            for (int reg = 0; reg < 16; ++reg) {
                const int r = m0 + wm + mf * 32 + (reg & 3) + 8 * (reg >> 2) + 4 * half;
                const int c = n0 + wn + nf * 32 + row32;
                C[(size_t)r * N + c] = acc[mf][nf][reg] + bia[nf];
            }
        }
    }
}

// float -> bf16 convert, 4 elems/thread
__global__ __launch_bounds__(256)
void cvt_bf16_kernel(const float* __restrict__ src, bf16_t* __restrict__ dst, int n)
{
    const int i = (blockIdx.x * 256 + threadIdx.x) * 4;
    if (i + 3 < n) {
        const float4 v = *reinterpret_cast<const float4*>(src + i);
        dst[i + 0] = (bf16_t)v.x;
        dst[i + 1] = (bf16_t)v.y;
        dst[i + 2] = (bf16_t)v.z;
        dst[i + 3] = (bf16_t)v.w;
    }
}

// out_w fp32 [2048][2048] -> slot-major bf16 Wp[ks][n][8]
__global__ __launch_bounds__(256)
void pack_wob_kernel(const float* __restrict__ W, bf16_t* __restrict__ Wp)
{
    const int idx = blockIdx.x * 256 + threadIdx.x;
    const int n = idx >> 8, ks = idx & 255;
    const float4 v0 = *reinterpret_cast<const float4*>(W + (size_t)n * 2048 + ks * 8);
    const float4 v1 = *reinterpret_cast<const float4*>(W + (size_t)n * 2048 + ks * 8 + 4);
    bf16x8 o;
    o[0] = (__bf16)v0.x; o[1] = (__bf16)v0.y; o[2] = (__bf16)v0.z; o[3] = (__bf16)v0.w;
    o[4] = (__bf16)v1.x; o[5] = (__bf16)v1.y; o[6] = (__bf16)v1.z; o[7] = (__bf16)v1.w;
    *reinterpret_cast<bf16x8*>(Wp + ((size_t)ks * 2048 + n) * 8) = o;
}

// Concat [B_w;C_w;dt_w] into bf16 [256,2048], rows 160..255 zero
__global__ __launch_bounds__(256)
void pack_w_kernel(const float* __restrict__ B_w, const float* __restrict__ C_w,
                   const float* __restrict__ dt_w, bf16_t* __restrict__ wcat)
{
    const int idx = blockIdx.x * 256 + threadIdx.x;
    const int r = idx >> 11, k = idx & 2047;
    float v = 0.f;
    if (r < 64)       v = B_w[r * 2048 + k];
    else if (r < 128) v = C_w[(r - 64) * 2048 + k];
    else if (r < 160) v = dt_w[(r - 128) * 2048 + k];
    wcat[idx] = (bf16_t)v;
}

// Per (b,h,chunk): Acs[l] = inclusive cumsum_l( dt[l] * A[h] ), A = -exp(A_log)
__global__ __launch_bounds__(kChunk)
void dtcumsum_kernel(const float* __restrict__ dtm, const float* __restrict__ A_log,
                     float* __restrict__ Acs)
{
    const int blk = blockIdx.x;
    const int ci = blk & (kNChunk - 1);
    const int hi = (blk >> 4) & (kHeads - 1);
    const int bi = blk >> 9;
    const int t = threadIdx.x;
    const float Ah = -expf(A_log[hi]);
    __shared__ float s[kChunk];
    s[t] = dtm[((size_t)bi * kSeq + ci * kChunk + t) * kHeads + hi] * Ah;
    __syncthreads();
    for (int off = 1; off < kChunk; off <<= 1) {
        const float add = (t >= off) ? s[t - off] : 0.f;
        __syncthreads();
        s[t] += add;
        __syncthreads();
    }
    Acs[((size_t)(bi * kHeads + hi) * kNChunk + ci) * kChunk + t] = s[t];
}

// Transpose one chunk of B: bTg[b,c][n][l] = Bb16[(b,c,l)][n]
__global__ __launch_bounds__(256)
void bT_kernel(const bf16_t* __restrict__ Bb16, bf16_t* __restrict__ bTg)
{
    const int ci = blockIdx.x & (kNChunk - 1);
    const int bi = blockIdx.x >> 4;
    const size_t rowbase = (size_t)bi * kSeq + ci * kChunk;
    __shared__ __bf16 T[64 * 264];
    const int tid = threadIdx.x;
    bf16x8 v[8];
    #pragma unroll
    for (int e = 0; e < 8; ++e)
        v[e] = *reinterpret_cast<const bf16x8*>(Bb16 + (rowbase + tid) * 64 + e * 8);
    #pragma unroll
    for (int e = 0; e < 8; ++e)
        #pragma unroll
        for (int j = 0; j < 8; ++j)
            T[(e * 8 + j) * 264 + tid] = v[e][j];
    __syncthreads();
    const int n = tid >> 2, seg = (tid & 3) * 64;
    bf16_t* dst = bTg + ((size_t)(bi * kNChunk + ci)) * (64 * 256) + n * 256 + seg;
    #pragma unroll
    for (int j = 0; j < 8; ++j) {
        *reinterpret_cast<bf16x8*>(dst + j * 8) =
            *reinterpret_cast<const bf16x8*>(&T[n * 264 + seg + j * 8]);
    }
}

// xdtT[(b,c,h)][p][l] = bf16( xb[t, h*64+p] * dt[t,h] ),  t = rowbase+l
__global__ __launch_bounds__(256)
void xdtT_kernel(const bf16_t* __restrict__ xb, const float* __restrict__ dtm,
                 bf16_t* __restrict__ xdtT)
{
    const int blk = blockIdx.x;
    const int hi = blk & (kHeads - 1);
    const int ci = (blk >> 5) & (kNChunk - 1);
    const int bi = blk >> 9;
    const size_t rowbase = (size_t)bi * kSeq + ci * kChunk;
    __shared__ __bf16 T[64 * 264];
    const int tid = threadIdx.x;
    const float d = dtm[(rowbase + tid) * kHeads + hi];
    bf16x8 v[8];
    #pragma unroll
    for (int e = 0; e < 8; ++e)
        v[e] = *reinterpret_cast<const bf16x8*>(xb + (rowbase + tid) * kDModel + hi * kP + e * 8);
    #pragma unroll
    for (int e = 0; e < 8; ++e)
        #pragma unroll
        for (int j = 0; j < 8; ++j)
            T[(e * 8 + j) * 264 + tid] = (__bf16)((float)v[e][j] * d);
    __syncthreads();
    const int p = tid >> 2, seg = (tid & 3) * 64;
    bf16_t* dst = xdtT + (size_t)blk * (64 * 256) + p * 256 + seg;
    #pragma unroll
    for (int j = 0; j < 8; ++j) {
        *reinterpret_cast<bf16x8*>(dst + j * 8) =
            *reinterpret_cast<const bf16x8*>(&T[p * 264 + seg + j * 8]);
    }
}

// ---------------------------------------------------------------------------
// MFMA chunk states: states[(b,c,h)][p][n] = sum_l xdtT[p][l]*dec[l]*B[l][n]
// ---------------------------------------------------------------------------
__global__ __launch_bounds__(256)
void states_mfma(const bf16_t* __restrict__ xdtT, const bf16_t* __restrict__ bTg,
                 const float* __restrict__ Acs, float* __restrict__ states)
{
    const int blk = blockIdx.x;
    const int hi = blk & (kHeads - 1);
    const int ci = (blk >> 5) & (kNChunk - 1);
    const int bi = blk >> 9;
    __shared__ __bf16 Xa[64 * 264];
    __shared__ __bf16 Bt[64 * 264];
    __shared__ float dec[kChunk];
    const int tid = threadIdx.x;
    const int lane = tid & 63;
    const int wave = tid >> 6;
    const int l15 = lane & 15, quad = lane >> 4;

    const float* acs = Acs + ((size_t)(bi * kHeads + hi) * kNChunk + ci) * kChunk;
    dec[tid] = expf(acs[kChunk - 1] - acs[tid]);   // <= 1
    __syncthreads();

    const bf16_t* bsrc = bTg + ((size_t)(bi * kNChunk + ci)) * (64 * 256);
    const bf16_t* xsrc = xdtT + (size_t)blk * (64 * 256);
    #pragma unroll
    for (int e = 0; e < 8; ++e) {
        const int u = e * 256 + tid;
        const int r = u >> 5, seg = (u & 31) * 8;
        *reinterpret_cast<bf16x8*>(&Bt[r * 264 + seg]) =
            *reinterpret_cast<const bf16x8*>(bsrc + r * 256 + seg);
        bf16x8 xv = *reinterpret_cast<const bf16x8*>(xsrc + r * 256 + seg);
        bf16x8 xo;
        #pragma unroll
        for (int j = 0; j < 8; ++j)
            xo[j] = (__bf16)((float)xv[j] * dec[seg + j]);
        *reinterpret_cast<bf16x8*>(&Xa[r * 264 + seg]) = xo;
    }
    __syncthreads();

    f32x4 acc[4];
    #pragma unroll
    for (int ni = 0; ni < 4; ++ni) acc[ni] = (f32x4){0.f, 0.f, 0.f, 0.f};
    #pragma unroll
    for (int kk = 0; kk < 8; ++kk) {
        const bf16x8 af = *reinterpret_cast<const bf16x8*>(
            &Xa[(wave * 16 + l15) * 264 + kk * 32 + quad * 8]);
        #pragma unroll
        for (int ni = 0; ni < 4; ++ni) {
            const bf16x8 bf = *reinterpret_cast<const bf16x8*>(
                &Bt[(ni * 16 + l15) * 264 + kk * 32 + quad * 8]);
            acc[ni] = __builtin_amdgcn_mfma_f32_16x16x32_bf16(af, bf, acc[ni], 0, 0, 0);
        }
    }
    float* sp = states + (size_t)blk * (kP * kState);
    #pragma unroll
    for (int reg = 0; reg < 4; ++reg) {
        const int p = wave * 16 + quad * 4 + reg;
        #pragma unroll
        for (int ni = 0; ni < 4; ++ni)
            sp[(size_t)p * kState + ni * 16 + l15] = acc[ni][reg];
    }
}

// prevs[b,0,h]=0 ; prevs[b,c,h] = exp(a[c-1])*prevs[b,c-1,h] + states[b,c-1,h]
// fp32 scan in registers, emits BF16.
__global__ __launch_bounds__(256)
void chunkscan_kernel(const float* __restrict__ states, const float* __restrict__ Acs,
                      bf16_t* __restrict__ prevsb)
{
    const int q  = blockIdx.x & 15;
    const int hi = (blockIdx.x >> 4) & (kHeads - 1);
    const int bi = blockIdx.x >> 9;
    const int e  = q * 256 + threadIdx.x;          // element in [0, 4096)
    __shared__ float ea[kNChunk];
    if (threadIdx.x < kNChunk)
        ea[threadIdx.x] = expf(Acs[((size_t)(bi * kHeads + hi) * kNChunk + threadIdx.x)
                                   * kChunk + kChunk - 1]);
    __syncthreads();
    float P = 0.f;
    prevsb[((size_t)(bi * kNChunk + 0) * kHeads + hi) * (kP * kState) + e] = (bf16_t)0.f;
    for (int c = 1; c < kNChunk; ++c) {
        P = fmaf(ea[c - 1], P,
                 states[((size_t)(bi * kNChunk + (c - 1)) * kHeads + hi) * (kP * kState) + e]);
        prevsb[((size_t)(bi * kNChunk + c) * kHeads + hi) * (kP * kState) + e] = (bf16_t)P;
    }
}

// ---------------------------------------------------------------------------
// MFMA intra-chunk Y — SPLIT structure (R2-proven, 4096 blocks, ~38KB LDS,
// 4 blocks/CU). Kept from R3: bf16 prevs staging (1 vec pass) and the x-free
// epilogue (x = xdt * (1/dt) from the resident Xt slice at st==lt).
// Output written SLOT-MAJOR: Yp[(hi*8+p/8)*kM + t][p%8].
// ---------------------------------------------------------------------------
__global__ __launch_bounds__(256)
void ychunk_mfma(const bf16_t* __restrict__ Bb16, const bf16_t* __restrict__ Cb16,
                 const bf16_t* __restrict__ xdtT, const float* __restrict__ Acs,
                 const bf16_t* __restrict__ prevsb, const float* __restrict__ dtm,
                 const float* __restrict__ Dvec, bf16_t* __restrict__ Yp)
{
    const int blk = blockIdx.x;                  // ((bi*16+ci)*32+hi)*4 + lt
    const int lt = blk & 3;
    const int hi = (blk >> 2) & (kHeads - 1);
    const int ci = (blk >> 7) & (kNChunk - 1);
    const int bi = blk >> 11;
    __shared__ float acs_s[kChunk];
    __shared__ float dts_s[64];
    __shared__ __bf16 Cs[64 * 72];
    __shared__ __bf16 Bs[64 * 72];   // P(bf16) first, then B s-tiles
    __shared__ __bf16 Xt[64 * 72];   // XdtT[p][s]
    __shared__ __bf16 Sp[64 * 72];   // S' [l][s]
    const int tid = threadIdx.x;
    const int lane = tid & 63;
    const int wave = tid >> 6;
    const int l15 = lane & 15, quad = lane >> 4;
    const int mrow = wave * 16 + quad * 4;
    const size_t rowbase = (size_t)bi * kSeq + ci * kChunk;
    const bf16_t* xdsrc = xdtT + ((size_t)((bi * kNChunk + ci) * kHeads + hi)) * (64 * 256);

    acs_s[tid] = Acs[((size_t)(bi * kHeads + hi) * kNChunk + ci) * kChunk + tid];
    if (tid < 64) dts_s[tid] = dtm[(rowbase + lt * 64 + tid) * kHeads + hi];
    // stage C l-tile and P (bf16, one vec pass) into Bs
    const bf16_t* pp = prevsb + ((size_t)(bi * kNChunk + ci) * kHeads + hi) * (kP * kState);
    #pragma unroll
    for (int e = 0; e < 2; ++e) {
        const int u = e * 256 + tid;
        const int r = u >> 3, seg = (u & 7) * 8;
        *reinterpret_cast<bf16x8*>(&Cs[r * 72 + seg]) =
            *reinterpret_cast<const bf16x8*>(Cb16 + (rowbase + lt * 64 + r) * 64 + seg);
        *reinterpret_cast<bf16x8*>(&Bs[r * 72 + seg]) =
            *reinterpret_cast<const bf16x8*>(pp + r * 64 + seg);
    }
    __syncthreads();

    // A-frags (C rows of this wave's slice) — reused for Y_off and every S-tile
    bf16x8 af[2];
    af[0] = *reinterpret_cast<const bf16x8*>(&Cs[(wave * 16 + l15) * 72 + quad * 8]);
    af[1] = *reinterpret_cast<const bf16x8*>(&Cs[(wave * 16 + l15) * 72 + 32 + quad * 8]);

    // Y_off = (C @ P^T) * exp(acs[l])
    f32x4 yacc[4];
    #pragma unroll
    for (int ni = 0; ni < 4; ++ni) yacc[ni] = (f32x4){0.f, 0.f, 0.f, 0.f};
    #pragma unroll
    for (int ni = 0; ni < 4; ++ni) {
        const bf16x8 b0 = *reinterpret_cast<const bf16x8*>(&Bs[(ni * 16 + l15) * 72 + quad * 8]);
        const bf16x8 b1 = *reinterpret_cast<const bf16x8*>(&Bs[(ni * 16 + l15) * 72 + 32 + quad * 8]);
        yacc[ni] = __builtin_amdgcn_mfma_f32_16x16x32_bf16(af[0], b0, yacc[ni], 0, 0, 0);
        yacc[ni] = __builtin_amdgcn_mfma_f32_16x16x32_bf16(af[1], b1, yacc[ni], 0, 0, 0);
    }
    {
        float es[4];
        #pragma unroll
        for (int reg = 0; reg < 4; ++reg) es[reg] = expf(acs_s[lt * 64 + mrow + reg]);
        #pragma unroll
        for (int ni = 0; ni < 4; ++ni)
            #pragma unroll
            for (int reg = 0; reg < 4; ++reg) yacc[ni][reg] *= es[reg];
    }

    for (int st = 0; st <= lt; ++st) {
        __syncthreads();   // everyone done reading Bs/Xt/Sp from previous stage
        // stage B s-tile and XdtT s-slice (pure vec copies)
        #pragma unroll
        for (int e = 0; e < 2; ++e) {
            const int u = e * 256 + tid;
            const int r = u >> 3, seg = (u & 7) * 8;
            *reinterpret_cast<bf16x8*>(&Bs[r * 72 + seg]) =
                *reinterpret_cast<const bf16x8*>(Bb16 + (rowbase + st * 64 + r) * 64 + seg);
            *reinterpret_cast<bf16x8*>(&Xt[r * 72 + seg]) =
                *reinterpret_cast<const bf16x8*>(xdsrc + r * 256 + st * 64 + seg);
        }
        __syncthreads();
        // S = C_lt(slice) @ B_st^T
        f32x4 sacc[4];
        #pragma unroll
        for (int ni = 0; ni < 4; ++ni) sacc[ni] = (f32x4){0.f, 0.f, 0.f, 0.f};
        #pragma unroll
        for (int ni = 0; ni < 4; ++ni) {
            const bf16x8 b0 = *reinterpret_cast<const bf16x8*>(&Bs[(ni * 16 + l15) * 72 + quad * 8]);
            const bf16x8 b1 = *reinterpret_cast<const bf16x8*>(&Bs[(ni * 16 + l15) * 72 + 32 + quad * 8]);
            sacc[ni] = __builtin_amdgcn_mfma_f32_16x16x32_bf16(af[0], b0, sacc[ni], 0, 0, 0);
            sacc[ni] = __builtin_amdgcn_mfma_f32_16x16x32_bf16(af[1], b1, sacc[ni], 0, 0, 0);
        }
        // decay + causal mask -> S' bf16
        #pragma unroll
        for (int reg = 0; reg < 4; ++reg) {
            const int l = lt * 64 + mrow + reg;
            const float al = acs_s[l];
            #pragma unroll
            for (int ni = 0; ni < 4; ++ni) {
                const int scol = ni * 16 + l15;
                const int sg = st * 64 + scol;
                float v = sacc[ni][reg] * expf(al - acs_s[sg]);
                if (st == lt && sg > l) v = 0.f;
                Sp[(mrow + reg) * 72 + scol] = (__bf16)v;
            }
        }
        __syncthreads();   // FENCE: S' writes visible before reads
        // Y += S' @ XdtT
        const bf16x8 as0 = *reinterpret_cast<const bf16x8*>(&Sp[(wave * 16 + l15) * 72 + quad * 8]);
        const bf16x8 as1 = *reinterpret_cast<const bf16x8*>(&Sp[(wave * 16 + l15) * 72 + 32 + quad * 8]);
        #pragma unroll
        for (int ni = 0; ni < 4; ++ni) {
            const bf16x8 x0 = *reinterpret_cast<const bf16x8*>(&Xt[(ni * 16 + l15) * 72 + quad * 8]);
            const bf16x8 x1 = *reinterpret_cast<const bf16x8*>(&Xt[(ni * 16 + l15) * 72 + 32 + quad * 8]);
            yacc[ni] = __builtin_amdgcn_mfma_f32_16x16x32_bf16(as0, x0, yacc[ni], 0, 0, 0);
            yacc[ni] = __builtin_amdgcn_mfma_f32_16x16x32_bf16(as1, x1, yacc[ni], 0, 0, 0);
        }
    }

    // epilogue: += D*x with x = xdt * (1/dt) from resident Xt (st==lt slice);
    // store bf16 Y in SLOT-MAJOR layout.
    const float Dh = Dvec[hi];
    #pragma unroll
    for (int reg = 0; reg < 4; ++reg) {
        const int lrow = mrow + reg;
        const size_t tg = rowbase + lt * 64 + lrow;
        const float dinv = 1.f / dts_s[lrow];
        #pragma unroll
        for (int ni = 0; ni < 4; ++ni) {
            const int p = ni * 16 + l15;
            const float xv = (float)Xt[p * 72 + lrow] * dinv;
            const float v = yacc[ni][reg] + Dh * xv;
            Yp[((size_t)(hi * 8 + (p >> 3)) * (size_t)kM + tg) * 8 + (p & 7)] = (bf16_t)v;
        }
    }
}

extern "C" void kernel_launch(void* const* d_in, const int* in_sizes, int n_in,
                              void* d_out, int out_size, void* d_ws, size_t ws_size,
                              hipStream_t stream)
{
    (void)in_sizes; (void)n_in; (void)out_size; (void)ws_size;
    const float* x     = (const float*)d_in[0];
    const float* A_log = (const float*)d_in[1];
    const float* Dvec  = (const float*)d_in[2];
    const float* B_w   = (const float*)d_in[3];
    const float* B_b   = (const float*)d_in[4];
    const float* C_w   = (const float*)d_in[5];
    const float* C_b   = (const float*)d_in[6];
    const float* dt_w  = (const float*)d_in[7];
    const float* dt_b  = (const float*)d_in[8];
    const float* out_w = (const float*)d_in[9];
    const float* out_b = (const float*)d_in[10];
    float* out = (float*)d_out;

    // workspace layout
    float* ws = (float*)d_ws;
    float* dtm    = ws;                                                  // 2*4096*32
    float* Acs    = dtm + (size_t)kM * kHeads;                           // 2*32*16*256
    float* states = Acs + (size_t)kBatch * kHeads * kNChunk * kChunk;    // fp32 states
    bf16_t* prevsb = (bf16_t*)(states + (size_t)kBatch * kNChunk * kHeads * kP * kState);
    bf16_t* xb    = prevsb + (size_t)kBatch * kNChunk * kHeads * kP * kState;
    bf16_t* Y     = xb;                               // ALIAS: xb dead after xdtT_kernel
    bf16_t* Bb16  = xb + (size_t)kM * kDModel;        // [t][64]
    bf16_t* Cb16  = Bb16 + (size_t)kM * kState;       // [t][64]
    bf16_t* xdtT  = Cb16 + (size_t)kM * kState;       // [(b,c,h)][64][256]
    bf16_t* bTg   = xdtT + (size_t)kM * kDModel;      // [(b,c)][64][256]
    bf16_t* wcat  = bTg + (size_t)kBatch * kNChunk * kState * kChunk;
    bf16_t* wob   = wcat + (size_t)256 * kDModel;     // bf16 out_w, slot-major [256][2048][8]

    const dim3 blk(256);
    cvt_bf16_kernel<<<dim3(kM * kDModel / 1024), blk, 0, stream>>>(x, xb, kM * kDModel);
    pack_wob_kernel<<<dim3(kDModel * 256 / 256), blk, 0, stream>>>(out_w, wob);
    pack_w_kernel<<<dim3(256 * kDModel / 256), blk, 0, stream>>>(B_w, C_w, dt_w, wcat);
    gemm_bcdt<<<dim3(2, kM / 64), blk, 0, stream>>>(xb, wcat, B_b, C_b, dt_b,
                                                    Bb16, Cb16, dtm);
    dtcumsum_kernel<<<dim3(kBatch * kHeads * kNChunk), dim3(kChunk), 0, stream>>>(dtm, A_log, Acs);
    bT_kernel<<<dim3(kBatch * kNChunk), blk, 0, stream>>>(Bb16, bTg);
    xdtT_kernel<<<dim3(kBatch * kNChunk * kHeads), blk, 0, stream>>>(xb, dtm, xdtT);
    states_mfma<<<dim3(kBatch * kNChunk * kHeads), blk, 0, stream>>>(xdtT, bTg, Acs, states);
    chunkscan_kernel<<<dim3(kBatch * kHeads * 16), blk, 0, stream>>>(states, Acs, prevsb);
    // intra-chunk Y: split over (b,c,h,lt) = 4096 blocks
    ychunk_mfma<<<dim3(kBatch * kNChunk * kHeads * 4), blk, 0, stream>>>(
        Bb16, Cb16, xdtT, Acs, prevsb, dtm, Dvec, Y);
    gemm256_out<<<dim3(256), dim3(512), 0, stream>>>(Y, wob, out_b, out);
}

// Round 5
// 353.326 us; speedup vs baseline: 1.0855x; 1.0323x over previous
//
#include <hip/hip_runtime.h>
#include <hip/hip_bf16.h>
#include <math.h>

namespace {
constexpr int kDModel = 2048;
constexpr int kHeads  = 32;
constexpr int kState  = 64;
constexpr int kP      = 64;    // head dim = D_MODEL / N_HEADS
constexpr int kChunk  = 256;
constexpr int kNChunk = 16;    // SEQLEN / CHUNK
constexpr int kBatch  = 2;
constexpr int kSeq    = 4096;
constexpr int kM      = kBatch * kSeq;  // 8192 rows
}

typedef __bf16 bf16_t;
typedef __attribute__((ext_vector_type(8))) __bf16 bf16x8;
typedef __attribute__((ext_vector_type(4))) __bf16 bf16x4;
typedef __attribute__((ext_vector_type(4))) float f32x4;

__device__ __forceinline__ void gload_lds16(const void* g, void* l) {
    __builtin_amdgcn_global_load_lds(
        (const __attribute__((address_space(1))) void*)g,
        (__attribute__((address_space(3))) void*)l,
        16, 0, 0);
}

// ---------------------------------------------------------------------------
// B/C/dt projection GEMM: 64x128 tile -> grid (2, 128) = 256 blocks.
// ---------------------------------------------------------------------------
__global__ __launch_bounds__(256)
void gemm_bcdt(const bf16_t* __restrict__ A, const bf16_t* __restrict__ W,
               const float* __restrict__ b0, const float* __restrict__ b1,
               const float* __restrict__ b2,
               bf16_t* __restrict__ o0h, bf16_t* __restrict__ o1h,
               float* __restrict__ o2f)
{
    constexpr int K = kDModel;
    __shared__ __bf16 AstS[64 * 32];
    __shared__ __bf16 WstS[128 * 32];
    const int tid  = threadIdx.x;
    const int lane = tid & 63;
    const int wave = tid >> 6;
    const int wm = (wave >> 1) * 32;
    const int wn = (wave & 1) * 64;
    const int l15 = lane & 15, quad = lane >> 4;
    const int m0 = blockIdx.y * 64;
    const int n0 = blockIdx.x * 128;
    const int u0 = tid, u1 = tid + 256;   // W staging 16B units

    f32x4 acc[2][4];
    #pragma unroll
    for (int i = 0; i < 2; ++i)
        #pragma unroll
        for (int j = 0; j < 4; ++j)
            acc[i][j] = (f32x4){0.f, 0.f, 0.f, 0.f};

    for (int k0 = 0; k0 < K; k0 += 32) {
        gload_lds16(A + (size_t)(m0 + (tid >> 2)) * K + k0 + (tid & 3) * 8, AstS + tid * 8);
        gload_lds16(W + (size_t)(n0 + (u0 >> 2)) * K + k0 + (u0 & 3) * 8, WstS + u0 * 8);
        gload_lds16(W + (size_t)(n0 + (u1 >> 2)) * K + k0 + (u1 & 3) * 8, WstS + u1 * 8);
        __syncthreads();
        bf16x8 af[2], bfr[4];
        #pragma unroll
        for (int mi = 0; mi < 2; ++mi)
            af[mi] = *reinterpret_cast<const bf16x8*>(&AstS[(wm + mi * 16 + l15) * 32 + quad * 8]);
        #pragma unroll
        for (int ni = 0; ni < 4; ++ni)
            bfr[ni] = *reinterpret_cast<const bf16x8*>(&WstS[(wn + ni * 16 + l15) * 32 + quad * 8]);
        #pragma unroll
        for (int mi = 0; mi < 2; ++mi)
            #pragma unroll
            for (int ni = 0; ni < 4; ++ni)
                acc[mi][ni] = __builtin_amdgcn_mfma_f32_16x16x32_bf16(
                    af[mi], bfr[ni], acc[mi][ni], 0, 0, 0);
        __syncthreads();
    }

    #pragma unroll
    for (int mi = 0; mi < 2; ++mi) {
        #pragma unroll
        for (int reg = 0; reg < 4; ++reg) {
            const int r = m0 + wm + mi * 16 + quad * 4 + reg;
            #pragma unroll
            for (int ni = 0; ni < 4; ++ni) {
                const float v = acc[mi][ni][reg];
                const int n = n0 + wn + ni * 16 + l15;
                if (n < 64) {
                    o0h[(size_t)r * 64 + n] = (bf16_t)(v + b0[n]);
                } else if (n < 128) {
                    o1h[(size_t)r * 64 + (n - 64)] = (bf16_t)(v + b1[n - 64]);
                } else if (n < 160) {
                    float z = v + b2[n - 128];
                    o2f[(size_t)r * 32 + (n - 128)] = (z > 20.f) ? z : log1pf(expf(z));
                }
            }
        }
    }
}

// ---------------------------------------------------------------------------
// Out-projection GEMM — EXACT R2-measured config (69.1 us, MfmaUtil 41%,
// FETCH 49.2 MB, VGPR 92): 256x256 tile, BK=32, 8 waves (2Mx4N), 16x16x32
// MFMA, triple-buffered LDS (96KB), raw s_barrier + counted vmcnt(4),
// slot-major LDS (conflict-free), m-panel-per-XCD swizzle.
// [R4 lesson: 32x32x16 variant = 83.5 us — same MFMA-busy time, +14 us
//  stall. Shape switch perturbs the schedule; do not re-try.]
// ---------------------------------------------------------------------------
__global__ __launch_bounds__(512, 2)
void gemm256_out(const bf16_t* __restrict__ Ap, const bf16_t* __restrict__ Bp,
                 const float* __restrict__ bias, float* __restrict__ C)
{
    constexpr int M = 8192, N = 2048, NT = 2048 / 32;  // 64 K-tiles
    __shared__ __bf16 Ab[3][4 * 256 * 8];   // [buf][slot*256 + row][8]
    __shared__ __bf16 Bb[3][4 * 256 * 8];
    const int tid  = threadIdx.x;
    const int lane = tid & 63;
    const int wave = tid >> 6;
    const int l15 = lane & 15, quad = lane >> 4;
    const int bid = blockIdx.x;
    const int mt = (bid & 7) * 4 + ((bid >> 3) & 3);   // 0..31
    const int nt = bid >> 5;                           // 0..7
    const int m0 = mt * 256;
    const int n0 = nt * 256;
    const int wm = (wave >> 2) * 128;   // 0 or 128
    const int wn = (wave & 3) * 64;     // 0,64,128,192

    const int u0 = tid, u1 = tid + 512;   // staging 16B units
    auto stage = [&](int t2, int stb) {
        const int ks0 = t2 * 4;
        const bf16_t* As = Ap + ((size_t)ks0 * M + m0) * 8;
        const bf16_t* Bs = Bp + ((size_t)ks0 * N + n0) * 8;
        __bf16* Al = &Ab[stb][0];
        __bf16* Bl = &Bb[stb][0];
        gload_lds16(As + ((size_t)(u0 >> 8) * M + (u0 & 255)) * 8, Al + u0 * 8);
        gload_lds16(As + ((size_t)(u1 >> 8) * M + (u1 & 255)) * 8, Al + u1 * 8);
        gload_lds16(Bs + ((size_t)(u0 >> 8) * N + (u0 & 255)) * 8, Bl + u0 * 8);
        gload_lds16(Bs + ((size_t)(u1 >> 8) * N + (u1 & 255)) * 8, Bl + u1 * 8);
    };

    f32x4 acc[8][4];
    #pragma unroll
    for (int i = 0; i < 8; ++i)
        #pragma unroll
        for (int j = 0; j < 4; ++j)
            acc[i][j] = (f32x4){0.f, 0.f, 0.f, 0.f};

    stage(0, 0);
    stage(1, 1);
    asm volatile("s_waitcnt vmcnt(4)" ::: "memory");
    __builtin_amdgcn_s_barrier();

    int cur = 0;
    for (int t = 0; t < NT; ++t) {
        const __bf16* Ac = &Ab[cur][0];
        const __bf16* Bc = &Bb[cur][0];
        int stb = cur + 2; if (stb >= 3) stb -= 3;

        // ---- phase A: frags (rows wm..wm+63) + all B frags; prefetch t+2
        bf16x8 af[4], bfr[4];
        #pragma unroll
        for (int mi = 0; mi < 4; ++mi)
            af[mi] = *reinterpret_cast<const bf16x8*>(
                &Ac[(quad * 256 + wm + mi * 16 + l15) * 8]);
        #pragma unroll
        for (int nj = 0; nj < 4; ++nj)
            bfr[nj] = *reinterpret_cast<const bf16x8*>(
                &Bc[(quad * 256 + wn + nj * 16 + l15) * 8]);
        if (t < NT - 2) stage(t + 2, stb);
        __builtin_amdgcn_s_setprio(1);
        #pragma unroll
        for (int mi = 0; mi < 4; ++mi)
            #pragma unroll
            for (int nj = 0; nj < 4; ++nj)
                acc[mi][nj] = __builtin_amdgcn_mfma_f32_16x16x32_bf16(
                    af[mi], bfr[nj], acc[mi][nj], 0, 0, 0);
        __builtin_amdgcn_s_setprio(0);

        // ---- phase B: frags (rows wm+64..wm+127), reuse B frags
        #pragma unroll
        for (int mi = 0; mi < 4; ++mi)
            af[mi] = *reinterpret_cast<const bf16x8*>(
                &Ac[(quad * 256 + wm + 64 + mi * 16 + l15) * 8]);
        __builtin_amdgcn_s_setprio(1);
        #pragma unroll
        for (int mi = 0; mi < 4; ++mi)
            #pragma unroll
            for (int nj = 0; nj < 4; ++nj)
                acc[4 + mi][nj] = __builtin_amdgcn_mfma_f32_16x16x32_bf16(
                    af[mi], bfr[nj], acc[4 + mi][nj], 0, 0, 0);
        __builtin_amdgcn_s_setprio(0);

        // ---- tile boundary: tile t+1 landed; t+2's 4 loads may fly
        if (t < NT - 2) {
            asm volatile("s_waitcnt vmcnt(4)" ::: "memory");
        } else if (t < NT - 1) {
            asm volatile("s_waitcnt vmcnt(0)" ::: "memory");
        }
        if (t < NT - 1) __builtin_amdgcn_s_barrier();
        cur = cur + 1; if (cur == 3) cur = 0;
    }

    // epilogue: C = acc + bias
    float bia[4];
    #pragma unroll
    for (int nj = 0; nj < 4; ++nj) bia[nj] = bias[n0 + wn + nj * 16 + l15];
    #pragma unroll
    for (int mi = 0; mi < 8; ++mi) {
        #pragma unroll
        for (int reg = 0; reg < 4; ++reg) {
            const int r = m0 + wm + mi * 16 + quad * 4 + reg;
            #pragma unroll
            for (int nj = 0; nj < 4; ++nj) {
                const int c = n0 + wn + nj * 16 + l15;
                C[(size_t)r * N + c] = acc[mi][nj][reg] + bia[nj];
            }
        }
    }
}

// ---------------------------------------------------------------------------
// Fused prep: cvt x->bf16 (16384 blocks) | pack out_w slot-major (2048) |
// pack [B_w;C_w;dt_w] (2048). Saves 2 kernel-launch gaps.
// ---------------------------------------------------------------------------
__global__ __launch_bounds__(256)
void prep_fused(const float* __restrict__ x, bf16_t* __restrict__ xb,
                const float* __restrict__ W, bf16_t* __restrict__ Wp,
                const float* __restrict__ B_w, const float* __restrict__ C_w,
                const float* __restrict__ dt_w, bf16_t* __restrict__ wcat)
{
    const int bid = blockIdx.x;
    if (bid < 16384) {
        // cvt_bf16: 4 elems/thread
        const int i = (bid * 256 + threadIdx.x) * 4;
        const float4 v = *reinterpret_cast<const float4*>(x + i);
        xb[i + 0] = (bf16_t)v.x;
        xb[i + 1] = (bf16_t)v.y;
        xb[i + 2] = (bf16_t)v.z;
        xb[i + 3] = (bf16_t)v.w;
    } else if (bid < 16384 + 2048) {
        // pack_wob: fp32 [2048][2048] -> slot-major bf16 Wp[ks][n][8]
        const int idx = (bid - 16384) * 256 + threadIdx.x;
        const int n = idx >> 8, ks = idx & 255;
        const float4 v0 = *reinterpret_cast<const float4*>(W + (size_t)n * 2048 + ks * 8);
        const float4 v1 = *reinterpret_cast<const float4*>(W + (size_t)n * 2048 + ks * 8 + 4);
        bf16x8 o;
        o[0] = (__bf16)v0.x; o[1] = (__bf16)v0.y; o[2] = (__bf16)v0.z; o[3] = (__bf16)v0.w;
        o[4] = (__bf16)v1.x; o[5] = (__bf16)v1.y; o[6] = (__bf16)v1.z; o[7] = (__bf16)v1.w;
        *reinterpret_cast<bf16x8*>(Wp + ((size_t)ks * 2048 + n) * 8) = o;
    } else {
        // pack_w: concat [B_w;C_w;dt_w] bf16 [256][2048], rows 160..255 zero
        const int idx = (bid - 16384 - 2048) * 256 + threadIdx.x;
        const int r = idx >> 11, k = idx & 2047;
        float v = 0.f;
        if (r < 64)       v = B_w[r * 2048 + k];
        else if (r < 128) v = C_w[(r - 64) * 2048 + k];
        else if (r < 160) v = dt_w[(r - 128) * 2048 + k];
        wcat[idx] = (bf16_t)v;
    }
}

// Per (b,h,chunk): Acs[l] = inclusive cumsum_l( dt[l] * A[h] ), A = -exp(A_log)
__global__ __launch_bounds__(kChunk)
void dtcumsum_kernel(const float* __restrict__ dtm, const float* __restrict__ A_log,
                     float* __restrict__ Acs)
{
    const int blk = blockIdx.x;
    const int ci = blk & (kNChunk - 1);
    const int hi = (blk >> 4) & (kHeads - 1);
    const int bi = blk >> 9;
    const int t = threadIdx.x;
    const float Ah = -expf(A_log[hi]);
    __shared__ float s[kChunk];
    s[t] = dtm[((size_t)bi * kSeq + ci * kChunk + t) * kHeads + hi] * Ah;
    __syncthreads();
    for (int off = 1; off < kChunk; off <<= 1) {
        const float add = (t >= off) ? s[t - off] : 0.f;
        __syncthreads();
        s[t] += add;
        __syncthreads();
    }
    Acs[((size_t)(bi * kHeads + hi) * kNChunk + ci) * kChunk + t] = s[t];
}

// Transpose one chunk of B: bTg[b,c][n][l] = Bb16[(b,c,l)][n]
__global__ __launch_bounds__(256)
void bT_kernel(const bf16_t* __restrict__ Bb16, bf16_t* __restrict__ bTg)
{
    const int ci = blockIdx.x & (kNChunk - 1);
    const int bi = blockIdx.x >> 4;
    const size_t rowbase = (size_t)bi * kSeq + ci * kChunk;
    __shared__ __bf16 T[64 * 264];
    const int tid = threadIdx.x;
    bf16x8 v[8];
    #pragma unroll
    for (int e = 0; e < 8; ++e)
        v[e] = *reinterpret_cast<const bf16x8*>(Bb16 + (rowbase + tid) * 64 + e * 8);
    #pragma unroll
    for (int e = 0; e < 8; ++e)
        #pragma unroll
        for (int j = 0; j < 8; ++j)
            T[(e * 8 + j) * 264 + tid] = v[e][j];
    __syncthreads();
    const int n = tid >> 2, seg = (tid & 3) * 64;
    bf16_t* dst = bTg + ((size_t)(bi * kNChunk + ci)) * (64 * 256) + n * 256 + seg;
    #pragma unroll
    for (int j = 0; j < 8; ++j) {
        *reinterpret_cast<bf16x8*>(dst + j * 8) =
            *reinterpret_cast<const bf16x8*>(&T[n * 264 + seg + j * 8]);
    }
}

// xdtT[(b,c,h)][p][l] = bf16( xb[t, h*64+p] * dt[t,h] ),  t = rowbase+l
__global__ __launch_bounds__(256)
void xdtT_kernel(const bf16_t* __restrict__ xb, const float* __restrict__ dtm,
                 bf16_t* __restrict__ xdtT)
{
    const int blk = blockIdx.x;
    const int hi = blk & (kHeads - 1);
    const int ci = (blk >> 5) & (kNChunk - 1);
    const int bi = blk >> 9;
    const size_t rowbase = (size_t)bi * kSeq + ci * kChunk;
    __shared__ __bf16 T[64 * 264];
    const int tid = threadIdx.x;
    const float d = dtm[(rowbase + tid) * kHeads + hi];
    bf16x8 v[8];
    #pragma unroll
    for (int e = 0; e < 8; ++e)
        v[e] = *reinterpret_cast<const bf16x8*>(xb + (rowbase + tid) * kDModel + hi * kP + e * 8);
    #pragma unroll
    for (int e = 0; e < 8; ++e)
        #pragma unroll
        for (int j = 0; j < 8; ++j)
            T[(e * 8 + j) * 264 + tid] = (__bf16)((float)v[e][j] * d);
    __syncthreads();
    const int p = tid >> 2, seg = (tid & 3) * 64;
    bf16_t* dst = xdtT + (size_t)blk * (64 * 256) + p * 256 + seg;
    #pragma unroll
    for (int j = 0; j < 8; ++j) {
        *reinterpret_cast<bf16x8*>(dst + j * 8) =
            *reinterpret_cast<const bf16x8*>(&T[p * 264 + seg + j * 8]);
    }
}

// ---------------------------------------------------------------------------
// MFMA chunk states: states[(b,c,h)][p][n] = sum_l xdtT[p][l]*dec[l]*B[l][n]
// ---------------------------------------------------------------------------
__global__ __launch_bounds__(256)
void states_mfma(const bf16_t* __restrict__ xdtT, const bf16_t* __restrict__ bTg,
                 const float* __restrict__ Acs, float* __restrict__ states)
{
    const int blk = blockIdx.x;
    const int hi = blk & (kHeads - 1);
    const int ci = (blk >> 5) & (kNChunk - 1);
    const int bi = blk >> 9;
    __shared__ __bf16 Xa[64 * 264];
    __shared__ __bf16 Bt[64 * 264];
    __shared__ float dec[kChunk];
    const int tid = threadIdx.x;
    const int lane = tid & 63;
    const int wave = tid >> 6;
    const int l15 = lane & 15, quad = lane >> 4;

    const float* acs = Acs + ((size_t)(bi * kHeads + hi) * kNChunk + ci) * kChunk;
    dec[tid] = expf(acs[kChunk - 1] - acs[tid]);   // <= 1
    __syncthreads();

    const bf16_t* bsrc = bTg + ((size_t)(bi * kNChunk + ci)) * (64 * 256);
    const bf16_t* xsrc = xdtT + (size_t)blk * (64 * 256);
    #pragma unroll
    for (int e = 0; e < 8; ++e) {
        const int u = e * 256 + tid;
        const int r = u >> 5, seg = (u & 31) * 8;
        *reinterpret_cast<bf16x8*>(&Bt[r * 264 + seg]) =
            *reinterpret_cast<const bf16x8*>(bsrc + r * 256 + seg);
        bf16x8 xv = *reinterpret_cast<const bf16x8*>(xsrc + r * 256 + seg);
        bf16x8 xo;
        #pragma unroll
        for (int j = 0; j < 8; ++j)
            xo[j] = (__bf16)((float)xv[j] * dec[seg + j]);
        *reinterpret_cast<bf16x8*>(&Xa[r * 264 + seg]) = xo;
    }
    __syncthreads();

    f32x4 acc[4];
    #pragma unroll
    for (int ni = 0; ni < 4; ++ni) acc[ni] = (f32x4){0.f, 0.f, 0.f, 0.f};
    #pragma unroll
    for (int kk = 0; kk < 8; ++kk) {
        const bf16x8 af = *reinterpret_cast<const bf16x8*>(
            &Xa[(wave * 16 + l15) * 264 + kk * 32 + quad * 8]);
        #pragma unroll
        for (int ni = 0; ni < 4; ++ni) {
            const bf16x8 bf = *reinterpret_cast<const bf16x8*>(
                &Bt[(ni * 16 + l15) * 264 + kk * 32 + quad * 8]);
            acc[ni] = __builtin_amdgcn_mfma_f32_16x16x32_bf16(af, bf, acc[ni], 0, 0, 0);
        }
    }
    float* sp = states + (size_t)blk * (kP * kState);
    #pragma unroll
    for (int reg = 0; reg < 4; ++reg) {
        const int p = wave * 16 + quad * 4 + reg;
        #pragma unroll
        for (int ni = 0; ni < 4; ++ni)
            sp[(size_t)p * kState + ni * 16 + l15] = acc[ni][reg];
    }
}

// prevs[b,0,h]=0 ; prevs[b,c,h] = exp(a[c-1])*prevs[b,c-1,h] + states[b,c-1,h]
// fp32 scan in registers, emits BF16.
__global__ __launch_bounds__(256)
void chunkscan_kernel(const float* __restrict__ states, const float* __restrict__ Acs,
                      bf16_t* __restrict__ prevsb)
{
    const int q  = blockIdx.x & 15;
    const int hi = (blockIdx.x >> 4) & (kHeads - 1);
    const int bi = blockIdx.x >> 9;
    const int e  = q * 256 + threadIdx.x;          // element in [0, 4096)
    __shared__ float ea[kNChunk];
    if (threadIdx.x < kNChunk)
        ea[threadIdx.x] = expf(Acs[((size_t)(bi * kHeads + hi) * kNChunk + threadIdx.x)
                                   * kChunk + kChunk - 1]);
    __syncthreads();
    float P = 0.f;
    prevsb[((size_t)(bi * kNChunk + 0) * kHeads + hi) * (kP * kState) + e] = (bf16_t)0.f;
    for (int c = 1; c < kNChunk; ++c) {
        P = fmaf(ea[c - 1], P,
                 states[((size_t)(bi * kNChunk + (c - 1)) * kHeads + hi) * (kP * kState) + e]);
        prevsb[((size_t)(bi * kNChunk + c) * kHeads + hi) * (kP * kState) + e] = (bf16_t)P;
    }
}

// ---------------------------------------------------------------------------
// MFMA intra-chunk Y — split structure (4096 blocks). NEW: the Sp buffer is
// WAVE-PRIVATE (wave w writes rows w*16..w*16+15 and reads exactly those
// rows), so the two block-wide barriers around the S' LDS roundtrip are
// replaced by a same-wave completion fence:
//   s_waitcnt lgkmcnt(0)  (writes retired)  +  sched_barrier(0) (no hoist).
// This removes ~5 block barriers per block from the serial critical path.
// ---------------------------------------------------------------------------
__global__ __launch_bounds__(256)
void ychunk_mfma(const bf16_t* __restrict__ Bb16, const bf16_t* __restrict__ Cb16,
                 const bf16_t* __restrict__ xdtT, const float* __restrict__ Acs,
                 const bf16_t* __restrict__ prevsb, const float* __restrict__ dtm,
                 const float* __restrict__ Dvec, bf16_t* __restrict__ Yp)
{
    const int blk = blockIdx.x;                  // ((bi*16+ci)*32+hi)*4 + lt
    const int lt = blk & 3;
    const int hi = (blk >> 2) & (kHeads - 1);
    const int ci = (blk >> 7) & (kNChunk - 1);
    const int bi = blk >> 11;
    __shared__ float acs_s[kChunk];
    __shared__ float dts_s[64];
    __shared__ __bf16 Cs[64 * 72];
    __shared__ __bf16 Bs[64 * 72];   // P(bf16) first, then B s-tiles
    __shared__ __bf16 Xt[64 * 72];   // XdtT[p][s]
    __shared__ __bf16 Sp[64 * 72];   // S' [l][s] — wave-private rows
    const int tid = threadIdx.x;
    const int lane = tid & 63;
    const int wave = tid >> 6;
    const int l15 = lane & 15, quad = lane >> 4;
    const int mrow = wave * 16 + quad * 4;
    const size_t rowbase = (size_t)bi * kSeq + ci * kChunk;
    const bf16_t* xdsrc = xdtT + ((size_t)((bi * kNChunk + ci) * kHeads + hi)) * (64 * 256);

    acs_s[tid] = Acs[((size_t)(bi * kHeads + hi) * kNChunk + ci) * kChunk + tid];
    if (tid < 64) dts_s[tid] = dtm[(rowbase + lt * 64 + tid) * kHeads + hi];
    // stage C l-tile and P (bf16, one vec pass) into Bs
    const bf16_t* pp = prevsb + ((size_t)(bi * kNChunk + ci) * kHeads + hi) * (kP * kState);
    #pragma unroll
    for (int e = 0; e < 2; ++e) {
        const int u = e * 256 + tid;
        const int r = u >> 3, seg = (u & 7) * 8;
        *reinterpret_cast<bf16x8*>(&Cs[r * 72 + seg]) =
            *reinterpret_cast<const bf16x8*>(Cb16 + (rowbase + lt * 64 + r) * 64 + seg);
        *reinterpret_cast<bf16x8*>(&Bs[r * 72 + seg]) =
            *reinterpret_cast<const bf16x8*>(pp + r * 64 + seg);
    }
    __syncthreads();

    // A-frags (C rows of this wave's slice) — reused for Y_off and every S-tile
    bf16x8 af[2];
    af[0] = *reinterpret_cast<const bf16x8*>(&Cs[(wave * 16 + l15) * 72 + quad * 8]);
    af[1] = *reinterpret_cast<const bf16x8*>(&Cs[(wave * 16 + l15) * 72 + 32 + quad * 8]);

    // Y_off = (C @ P^T) * exp(acs[l])
    f32x4 yacc[4];
    #pragma unroll
    for (int ni = 0; ni < 4; ++ni) yacc[ni] = (f32x4){0.f, 0.f, 0.f, 0.f};
    #pragma unroll
    for (int ni = 0; ni < 4; ++ni) {
        const bf16x8 b0 = *reinterpret_cast<const bf16x8*>(&Bs[(ni * 16 + l15) * 72 + quad * 8]);
        const bf16x8 b1 = *reinterpret_cast<const bf16x8*>(&Bs[(ni * 16 + l15) * 72 + 32 + quad * 8]);
        yacc[ni] = __builtin_amdgcn_mfma_f32_16x16x32_bf16(af[0], b0, yacc[ni], 0, 0, 0);
        yacc[ni] = __builtin_amdgcn_mfma_f32_16x16x32_bf16(af[1], b1, yacc[ni], 0, 0, 0);
    }
    {
        float es[4];
        #pragma unroll
        for (int reg = 0; reg < 4; ++reg) es[reg] = expf(acs_s[lt * 64 + mrow + reg]);
        #pragma unroll
        for (int ni = 0; ni < 4; ++ni)
            #pragma unroll
            for (int reg = 0; reg < 4; ++reg) yacc[ni][reg] *= es[reg];
    }

    for (int st = 0; st <= lt; ++st) {
        __syncthreads();   // everyone done reading Bs/Xt from previous stage
        // stage B s-tile and XdtT s-slice (pure vec copies)
        #pragma unroll
        for (int e = 0; e < 2; ++e) {
            const int u = e * 256 + tid;
            const int r = u >> 3, seg = (u & 7) * 8;
            *reinterpret_cast<bf16x8*>(&Bs[r * 72 + seg]) =
                *reinterpret_cast<const bf16x8*>(Bb16 + (rowbase + st * 64 + r) * 64 + seg);
            *reinterpret_cast<bf16x8*>(&Xt[r * 72 + seg]) =
                *reinterpret_cast<const bf16x8*>(xdsrc + r * 256 + st * 64 + seg);
        }
        __syncthreads();
        // S = C_lt(slice) @ B_st^T
        f32x4 sacc[4];
        #pragma unroll
        for (int ni = 0; ni < 4; ++ni) sacc[ni] = (f32x4){0.f, 0.f, 0.f, 0.f};
        #pragma unroll
        for (int ni = 0; ni < 4; ++ni) {
            const bf16x8 b0 = *reinterpret_cast<const bf16x8*>(&Bs[(ni * 16 + l15) * 72 + quad * 8]);
            const bf16x8 b1 = *reinterpret_cast<const bf16x8*>(&Bs[(ni * 16 + l15) * 72 + 32 + quad * 8]);
            sacc[ni] = __builtin_amdgcn_mfma_f32_16x16x32_bf16(af[0], b0, sacc[ni], 0, 0, 0);
            sacc[ni] = __builtin_amdgcn_mfma_f32_16x16x32_bf16(af[1], b1, sacc[ni], 0, 0, 0);
        }
        // decay + causal mask -> S' bf16 (wave-private rows of Sp)
        #pragma unroll
        for (int reg = 0; reg < 4; ++reg) {
            const int l = lt * 64 + mrow + reg;
            const float al = acs_s[l];
            #pragma unroll
            for (int ni = 0; ni < 4; ++ni) {
                const int scol = ni * 16 + l15;
                const int sg = st * 64 + scol;
                float v = sacc[ni][reg] * expf(al - acs_s[sg]);
                if (st == lt && sg > l) v = 0.f;
                Sp[(mrow + reg) * 72 + scol] = (__bf16)v;
            }
        }
        // same-wave fence replaces __syncthreads: Sp rows are wave-private.
        asm volatile("s_waitcnt lgkmcnt(0)" ::: "memory");
        __builtin_amdgcn_sched_barrier(0);
        // Y += S' @ XdtT
        const bf16x8 as0 = *reinterpret_cast<const bf16x8*>(&Sp[(wave * 16 + l15) * 72 + quad * 8]);
        const bf16x8 as1 = *reinterpret_cast<const bf16x8*>(&Sp[(wave * 16 + l15) * 72 + 32 + quad * 8]);
        #pragma unroll
        for (int ni = 0; ni < 4; ++ni) {
            const bf16x8 x0 = *reinterpret_cast<const bf16x8*>(&Xt[(ni * 16 + l15) * 72 + quad * 8]);
            const bf16x8 x1 = *reinterpret_cast<const bf16x8*>(&Xt[(ni * 16 + l15) * 72 + 32 + quad * 8]);
            yacc[ni] = __builtin_amdgcn_mfma_f32_16x16x32_bf16(as0, x0, yacc[ni], 0, 0, 0);
            yacc[ni] = __builtin_amdgcn_mfma_f32_16x16x32_bf16(as1, x1, yacc[ni], 0, 0, 0);
        }
        // no end-of-iteration barrier: the loop-top barrier protects re-stage
    }

    // epilogue: += D*x with x = xdt * (1/dt) from resident Xt (st==lt slice);
    // store bf16 Y in SLOT-MAJOR layout.
    const float Dh = Dvec[hi];
    #pragma unroll
    for (int reg = 0; reg < 4; ++reg) {
        const int lrow = mrow + reg;
        const size_t tg = rowbase + lt * 64 + lrow;
        const float dinv = 1.f / dts_s[lrow];
        #pragma unroll
        for (int ni = 0; ni < 4; ++ni) {
            const int p = ni * 16 + l15;
            const float xv = (float)Xt[p * 72 + lrow] * dinv;
            const float v = yacc[ni][reg] + Dh * xv;
            Yp[((size_t)(hi * 8 + (p >> 3)) * (size_t)kM + tg) * 8 + (p & 7)] = (bf16_t)v;
        }
    }
}

extern "C" void kernel_launch(void* const* d_in, const int* in_sizes, int n_in,
                              void* d_out, int out_size, void* d_ws, size_t ws_size,
                              hipStream_t stream)
{
    (void)in_sizes; (void)n_in; (void)out_size; (void)ws_size;
    const float* x     = (const float*)d_in[0];
    const float* A_log = (const float*)d_in[1];
    const float* Dvec  = (const float*)d_in[2];
    const float* B_w   = (const float*)d_in[3];
    const float* B_b   = (const float*)d_in[4];
    const float* C_w   = (const float*)d_in[5];
    const float* C_b   = (const float*)d_in[6];
    const float* dt_w  = (const float*)d_in[7];
    const float* dt_b  = (const float*)d_in[8];
    const float* out_w = (const float*)d_in[9];
    const float* out_b = (const float*)d_in[10];
    float* out = (float*)d_out;

    // workspace layout
    float* ws = (float*)d_ws;
    float* dtm    = ws;                                                  // 2*4096*32
    float* Acs    = dtm + (size_t)kM * kHeads;                           // 2*32*16*256
    float* states = Acs + (size_t)kBatch * kHeads * kNChunk * kChunk;    // fp32 states
    bf16_t* prevsb = (bf16_t*)(states + (size_t)kBatch * kNChunk * kHeads * kP * kState);
    bf16_t* xb    = prevsb + (size_t)kBatch * kNChunk * kHeads * kP * kState;
    bf16_t* Y     = xb;                               // ALIAS: xb dead after xdtT_kernel
    bf16_t* Bb16  = xb + (size_t)kM * kDModel;        // [t][64]
    bf16_t* Cb16  = Bb16 + (size_t)kM * kState;       // [t][64]
    bf16_t* xdtT  = Cb16 + (size_t)kM * kState;       // [(b,c,h)][64][256]
    bf16_t* bTg   = xdtT + (size_t)kM * kDModel;      // [(b,c)][64][256]
    bf16_t* wcat  = bTg + (size_t)kBatch * kNChunk * kState * kChunk;
    bf16_t* wob   = wcat + (size_t)256 * kDModel;     // bf16 out_w, slot-major [256][2048][8]

    const dim3 blk(256);
    // fused prep: cvt x (16384) | pack out_w (2048) | pack BCdt (2048)
    prep_fused<<<dim3(16384 + 2048 + 2048), blk, 0, stream>>>(
        x, xb, out_w, wob, B_w, C_w, dt_w, wcat);
    gemm_bcdt<<<dim3(2, kM / 64), blk, 0, stream>>>(xb, wcat, B_b, C_b, dt_b,
                                                    Bb16, Cb16, dtm);
    dtcumsum_kernel<<<dim3(kBatch * kHeads * kNChunk), dim3(kChunk), 0, stream>>>(dtm, A_log, Acs);
    bT_kernel<<<dim3(kBatch * kNChunk), blk, 0, stream>>>(Bb16, bTg);
    xdtT_kernel<<<dim3(kBatch * kNChunk * kHeads), blk, 0, stream>>>(xb, dtm, xdtT);
    states_mfma<<<dim3(kBatch * kNChunk * kHeads), blk, 0, stream>>>(xdtT, bTg, Acs, states);
    chunkscan_kernel<<<dim3(kBatch * kHeads * 16), blk, 0, stream>>>(states, Acs, prevsb);
    // intra-chunk Y: split over (b,c,h,lt) = 4096 blocks
    ychunk_mfma<<<dim3(kBatch * kNChunk * kHeads * 4), blk, 0, stream>>>(
        Bb16, Cb16, xdtT, Acs, prevsb, dtm, Dvec, Y);
    gemm256_out<<<dim3(256), dim3(512), 0, stream>>>(Y, wob, out_b, out);
}